// Round 16
// baseline (2431.099 us; speedup 1.0000x reference)
//
#include <hip/hip_runtime.h>
#include <math.h>

typedef unsigned short u16;
typedef unsigned char u8;
typedef short v8s __attribute__((ext_vector_type(8)));
typedef u16   v4u __attribute__((ext_vector_type(4)));
typedef float v4f __attribute__((ext_vector_type(4)));
typedef int   v2i __attribute__((ext_vector_type(2)));
typedef int   v4i __attribute__((ext_vector_type(4)));

#define DEVFN static __device__ __forceinline__

constexpr int cB = 2, cS = 4096, cD = 2048, cV = 32000, cH = 16, cHD = 128;
constexpr int cBS = 16, cNA = 128, cMASK = 31999, cDFF = 8192;
constexpr int NCAND = cS - cBS + 1;   // 4081 anchor candidates
constexpr int MTOK  = cB * cNA * cBS; // 4096 query tokens
constexpr int MKV   = cB * cNA * 17;  // 4352 kv rows (ctx + 16)
constexpr int NCH   = cV / 128;       // 250 vocab chunks (128-wide, fallback)
constexpr int NCH2  = cV / 256;       // 125 vocab chunks (256-wide, fast)

constexpr int EPI_BF16 = 0, EPI_SILU = 1, EPI_OEMB = 2, EPI_DOWNACC = 3, EPI_STATS = 4, EPI_GLU = 5;
constexpr int ASRC_BF16 = 0, ASRC_RMS = 1, ASRC_AOMAP = 2;

struct RmsSrc {
  const float* hs; const float* emb; const float* nattn; const float* nchs;
  const float* rowinv; const int* ftok; const int* cpos;
};

DEVFN u16 f2bf(float f) {               // RNE fp32 -> bf16
  union { float f; unsigned u; } a; a.f = f;
  unsigned u = a.u;
  u = u + 0x7fffu + ((u >> 16) & 1u);
  return (u16)(u >> 16);
}
DEVFN float bf2f(u16 h) {
  union { unsigned u; float f; } a; a.u = ((unsigned)h) << 16;
  return a.f;
}
DEVFN float waveSum(float v) {
  #pragma unroll
  for (int o = 32; o >= 1; o >>= 1) v += __shfl_xor(v, o);
  return v;
}
DEVFN void gload16(void* lds, const void* g) {
  __builtin_amdgcn_global_load_lds(
      (const __attribute__((address_space(1))) unsigned*)g,
      (__attribute__((address_space(3))) unsigned*)lds, 16, 0, 0);
}
DEVFN int pack4fp8(float a, float b, float c, float d) {
  int p = __builtin_amdgcn_cvt_pk_fp8_f32(a, b, 0, 0);
  p = __builtin_amdgcn_cvt_pk_fp8_f32(c, d, p, 1);
  return p;
}
DEVFN u8 f2fp8(float v) {
  return (u8)(__builtin_amdgcn_cvt_pk_fp8_f32(v, 0.f, 0, 0) & 0xff);
}
// permuted output offset for fp8 buffers: within each 64B K-group,
// newpos = lq*16 + kh*8 + j  for k = kh*32 + lq*8 + j
DEVFN long perm8(long i) {
  return (i & ~63L) | (((i >> 3) & 3) << 4) | (((i >> 5) & 1) << 3);
}

// ---------------------------------------------------------------------------
__global__ void k_select(const float* __restrict__ lmask, const float* __restrict__ rv_in,
                         int* __restrict__ self) {
  int b = blockIdx.x >> 4, chunk = blockIdx.x & 15;
  __shared__ float rvs[4096];
  for (int i = threadIdx.x; i < NCAND; i += 256) {
    bool valid = lmask[(size_t)b * cS + i] > 0.5f;
    rvs[i] = valid ? rv_in[(size_t)b * NCAND + i] : 2.0f;
  }
  __syncthreads();
  int i = chunk * 256 + threadIdx.x;
  if (i < NCAND) {
    float v = rvs[i];
    int rank = 0;
    for (int j = 0; j < NCAND; ++j) {
      float u = rvs[j];
      rank += (u < v) || (u == v && j < i);
    }
    self[(size_t)b * NCAND + i] = (rank < cNA) ? 1 : 0;
  }
}

__global__ void k_anchors(const float* __restrict__ lmask, const int* __restrict__ self,
                          const int* __restrict__ ids, int* __restrict__ anchors,
                          int* __restrict__ keepA, int* __restrict__ ftok, int* __restrict__ cpos) {
  int b = blockIdx.x;
  __shared__ int flags[4096];
  __shared__ int ssum[256];
  __shared__ int soff[257];
  __shared__ int abuf[cNA];
  for (int i = threadIdx.x; i < 4096; i += 256)
    flags[i] = (i < NCAND) ? (self[(size_t)b * NCAND + i] && (lmask[(size_t)b * cS + i] > 0.5f)) : 0;
  if (threadIdx.x < cNA) abuf[threadIdx.x] = 0;
  __syncthreads();
  int s = 0;
  #pragma unroll
  for (int j = 0; j < 16; ++j) s += flags[threadIdx.x * 16 + j];
  ssum[threadIdx.x] = s;
  __syncthreads();
  if (threadIdx.x == 0) {
    int a = 0;
    for (int t = 0; t < 256; ++t) { soff[t] = a; a += ssum[t]; }
    soff[256] = a;
  }
  __syncthreads();
  int nsel = soff[256];
  int p = soff[threadIdx.x];
  for (int j = 0; j < 16; ++j) {
    int i = threadIdx.x * 16 + j;
    if (flags[i]) { if (p < cNA) abuf[p] = i; ++p; }
  }
  __syncthreads();
  if (threadIdx.x < cNA) {
    int q = threadIdx.x;
    int kp = (q < nsel) ? 1 : 0;
    int a = kp ? abuf[q] : 0;
    anchors[b * cNA + q] = a;
    keepA[b * cNA + q] = kp;
    int av = a; if (av < 0) av = 0; if (av > cS - 1) av = cS - 1;
    int tok = ids[(size_t)b * cS + av];
    ftok[b * cNA + q] = kp ? tok : cMASK;
    cpos[b * cNA + q] = (a - 1 > 0) ? (a - 1) : 0;
  }
}

// per-kv-row 1/rms (fallback tier)
__global__ void k_rowinv(const float* __restrict__ hs, const float* __restrict__ emb,
                         const int* __restrict__ ftok, const int* __restrict__ cpos,
                         float* __restrict__ rowinv) {
  int r = blockIdx.x;
  int j = r % 17, bn = r / 17, b = bn >> 7;
  const float* src = (j == 0) ? hs + ((size_t)b * cS + cpos[bn]) * cD
                              : emb + (size_t)((j == 1) ? ftok[bn] : cMASK) * cD;
  float ss = 0.f;
  for (int d = threadIdx.x; d < cD; d += 256) { float v = src[d]; ss += v * v; }
  ss = waveSum(ss);
  __shared__ float red[4];
  if ((threadIdx.x & 63) == 0) red[threadIdx.x >> 6] = ss;
  __syncthreads();
  if (threadIdx.x == 0) {
    float tot = red[0] + red[1] + red[2] + red[3];
    rowinv[r] = 1.0f / sqrtf(tot / cD + 1e-6f);
  }
}

// kv_in = rms'd rows, materialized fp8 perm8 (fast tier). grid: MKV x 256
__global__ void k_build2(const float* __restrict__ hs, const float* __restrict__ emb,
                         const float* __restrict__ nattn, const float* __restrict__ nchs,
                         const int* __restrict__ ftok, const int* __restrict__ cpos,
                         u8* __restrict__ kv8) {
  int r = blockIdx.x;
  int j = r % 17, bn = r / 17, b = bn >> 7;
  const float* src; const float* w;
  if (j == 0) { src = hs + ((size_t)b * cS + cpos[bn]) * cD; w = nchs; }
  else {
    int tok = (j == 1) ? ftok[bn] : cMASK;
    src = emb + (size_t)tok * cD; w = nattn;
  }
  float ss = 0.f;
  for (int d = threadIdx.x; d < cD; d += 256) { float v = src[d]; ss += v * v; }
  ss = waveSum(ss);
  __shared__ float red[4];
  if ((threadIdx.x & 63) == 0) red[threadIdx.x >> 6] = ss;
  __syncthreads();
  float tot = red[0] + red[1] + red[2] + red[3];
  float inv = 1.0f / sqrtf(tot / cD + 1e-6f);
  for (int d = threadIdx.x; d < cD; d += 256)
    kv8[perm8((size_t)r * cD + d)] = f2fp8(src[d] * inv * w[d]);
}

// RMS over fp32 rows -> bf16
__global__ void k_rms(const float* __restrict__ xin, const float* __restrict__ w,
                      u16* __restrict__ outp) {
  int m = blockIdx.x;
  const float* row = xin + (size_t)m * cD;
  float ss = 0.f;
  for (int d = threadIdx.x; d < cD; d += 256) { float v = row[d]; ss += v * v; }
  ss = waveSum(ss);
  __shared__ float red[4];
  if ((threadIdx.x & 63) == 0) red[threadIdx.x >> 6] = ss;
  __syncthreads();
  float tot = red[0] + red[1] + red[2] + red[3];
  float inv = 1.0f / sqrtf(tot / cD + 1e-6f);
  for (int d = threadIdx.x; d < cD; d += 256)
    outp[(size_t)m * cD + d] = f2bf(row[d] * inv * w[d]);
}

// fp32 -> fp8 e4m3 with scale, PERMUTED 64B-group layout. 8 elems/thread
__global__ void k_conv8(const float* __restrict__ in, u8* __restrict__ out, long n, float scale) {
  long i = ((long)blockIdx.x * 256 + threadIdx.x) * 8;
  long stride = (long)gridDim.x * 256 * 8;
  for (; i < n; i += stride) {
    v4f a = *(const v4f*)(in + i), b = *(const v4f*)(in + i + 4);
    v2i pk;
    pk[0] = pack4fp8(a[0] * scale, a[1] * scale, a[2] * scale, a[3] * scale);
    pk[1] = pack4fp8(b[0] * scale, b[1] * scale, b[2] * scale, b[3] * scale);
    *(v2i*)(out + perm8(i)) = pk;
  }
}

// bf16 -> fp8 e4m3, PERMUTED 64B-group layout. 8 elems/thread
__global__ void k_cvt8(const u16* __restrict__ in, u8* __restrict__ out, long n) {
  long i = ((long)blockIdx.x * 256 + threadIdx.x) * 8;
  long stride = (long)gridDim.x * 256 * 8;
  for (; i < n; i += stride) {
    v8s a = *(const v8s*)(in + i);
    v2i pk;
    pk[0] = pack4fp8(bf2f((u16)a[0]), bf2f((u16)a[1]), bf2f((u16)a[2]), bf2f((u16)a[3]));
    pk[1] = pack4fp8(bf2f((u16)a[4]), bf2f((u16)a[5]), bf2f((u16)a[6]), bf2f((u16)a[7]));
    *(v2i*)(out + perm8(i)) = pk;
  }
}

// transpose + fp8(scale) + perm8; goff>=0: gate/up interleave (col j -> row
// (j>>4)*32+goff+(j&15)); goff<0: plain (row = col j)
__global__ void k_tconv8(const float* __restrict__ W, u8* __restrict__ WT8,
                         int K, int N, int goff, float scale) {
  __shared__ float tf[64][65];
  int n0 = blockIdx.x * 64, k0 = blockIdx.y * 64;
  int tid = threadIdx.x;
  int c4 = (tid & 15) * 4, r0 = tid >> 4;
  #pragma unroll
  for (int rr = 0; rr < 64; rr += 16) {
    int k = r0 + rr;
    v4f v = *(const v4f*)(W + (size_t)(k0 + k) * N + n0 + c4);
    #pragma unroll
    for (int e = 0; e < 4; ++e) tf[c4 + e][k] = v[e];
  }
  __syncthreads();
  int n = tid >> 2, kq = (tid & 3) * 16;
  int gn = n0 + n;
  size_t rout = (goff >= 0) ? (((size_t)(gn >> 4) << 5) + goff + (gn & 15)) : (size_t)gn;
  long base = (long)rout * K + k0 + kq;
  v2i p0, p1;
  p0[0] = pack4fp8(tf[n][kq + 0] * scale, tf[n][kq + 1] * scale, tf[n][kq + 2] * scale, tf[n][kq + 3] * scale);
  p0[1] = pack4fp8(tf[n][kq + 4] * scale, tf[n][kq + 5] * scale, tf[n][kq + 6] * scale, tf[n][kq + 7] * scale);
  p1[0] = pack4fp8(tf[n][kq + 8] * scale, tf[n][kq + 9] * scale, tf[n][kq + 10] * scale, tf[n][kq + 11] * scale);
  p1[1] = pack4fp8(tf[n][kq + 12] * scale, tf[n][kq + 13] * scale, tf[n][kq + 14] * scale, tf[n][kq + 15] * scale);
  *(v2i*)(WT8 + perm8(base)) = p0;
  *(v2i*)(WT8 + perm8(base + 8)) = p1;
}

// ---------------------------------------------------------------------------
// 8-PHASE PIPELINED 256x256 GEMM fp8 e4m3 (round-12 verified double-buffer):
// b128 fragment reads, 64KB LDS (2 blk/CU), t+2 lookahead, vmcnt(4).
// EPI_GLU: interleaved gate/up, out fp8 perm8 = up * silu(gate) (acc/64).
template <int EPI>
__launch_bounds__(512, 2)
__global__ void k_gemm8(const u8* __restrict__ A8, const u8* __restrict__ B8,
                        u8* __restrict__ C8, v4f* __restrict__ partials,
                        int K, int ldc, int nch) {
  __shared__ __align__(16) u8 lds8[65536];
  const int tid = threadIdx.x;
  const int lane = tid & 63, wid = tid >> 6;
  const int wm = wid >> 2, wn = wid & 3;        // per-wave out 128x64
  const int lc = lane & 15, lq = lane >> 4;
  const int m0 = blockIdx.x * 256, n0 = blockIdx.y * 256;

  const u8* srcA[2]; const u8* srcB[2];
  #pragma unroll
  for (int i = 0; i < 2; ++i) {
    int ci = i * 512 + tid;
    int r = ci >> 2;
    int logc = (ci & 3) ^ ((r >> 1) & 3);
    srcA[i] = A8 + (size_t)(m0 + r) * K + logc * 16;
    srcB[i] = B8 + (size_t)(n0 + r) * K + logc * 16;
  }

  v4f acc[8][4];
  #pragma unroll
  for (int i = 0; i < 8; ++i)
    #pragma unroll
    for (int j = 0; j < 4; ++j) acc[i][j] = (v4f){0.f, 0.f, 0.f, 0.f};

  const int csw = (lc >> 1) & 3;
  int aoff[8], boff[4];
  #pragma unroll
  for (int mi = 0; mi < 8; ++mi) aoff[mi] = (wm * 128 + mi * 16 + lc) * 64 + ((lq ^ csw) << 4);
  #pragma unroll
  for (int ni = 0; ni < 4; ++ni) boff[ni] = (wn * 64 + ni * 16 + lc) * 64 + ((lq ^ csw) << 4);

  auto stageA = [&](int t, int i) {
    gload16(&lds8[(t & 1) * 32768 + i * 8192 + wid * 1024], srcA[i] + t * 64);
  };
  auto stageB = [&](int t, int i) {
    gload16(&lds8[(t & 1) * 32768 + 16384 + i * 8192 + wid * 1024], srcB[i] + t * 64);
  };

  stageA(0, 0); stageA(0, 1); stageB(0, 0); stageB(0, 1);
  stageA(1, 0); stageA(1, 1); stageB(1, 0); stageB(1, 1);
  asm volatile("s_waitcnt vmcnt(4)" ::: "memory");
  __builtin_amdgcn_s_barrier();

  union Frag { v4i v; long long ll[2]; };
  const int NT = K >> 6;
  for (int t = 0; t < NT; ++t) {
    const u8* Ab = &lds8[(t & 1) * 32768];
    const u8* Bb = Ab + 16384;
    Frag fa[8], fb[4];

    #pragma unroll
    for (int ni = 0; ni < 4; ++ni) fb[ni].v = *(const v4i*)(Bb + boff[ni]);
    #pragma unroll
    for (int mi = 0; mi < 4; ++mi) fa[mi].v = *(const v4i*)(Ab + aoff[mi]);
    asm volatile("s_waitcnt lgkmcnt(0)" ::: "memory");
    __builtin_amdgcn_sched_barrier(0);
    __builtin_amdgcn_s_setprio(1);
    #pragma unroll
    for (int mi = 0; mi < 4; ++mi)
      #pragma unroll
      for (int ni = 0; ni < 4; ++ni)
        acc[mi][ni] = __builtin_amdgcn_mfma_f32_16x16x32_fp8_fp8(fa[mi].ll[0], fb[ni].ll[0], acc[mi][ni], 0, 0, 0);
    __builtin_amdgcn_s_setprio(0);
    __builtin_amdgcn_s_barrier();

    #pragma unroll
    for (int mi = 0; mi < 4; ++mi) fa[mi + 4].v = *(const v4i*)(Ab + aoff[mi + 4]);
    if (t + 2 < NT) stageB(t + 2, 0);
    asm volatile("s_waitcnt lgkmcnt(0)" ::: "memory");
    __builtin_amdgcn_sched_barrier(0);
    __builtin_amdgcn_s_setprio(1);
    #pragma unroll
    for (int mi = 0; mi < 4; ++mi)
      #pragma unroll
      for (int ni = 0; ni < 4; ++ni)
        acc[mi + 4][ni] = __builtin_amdgcn_mfma_f32_16x16x32_fp8_fp8(fa[mi + 4].ll[0], fb[ni].ll[0], acc[mi + 4][ni], 0, 0, 0);
    __builtin_amdgcn_s_setprio(0);
    __builtin_amdgcn_s_barrier();

    if (t + 2 < NT) { stageB(t + 2, 1); stageA(t + 2, 0); }
    __builtin_amdgcn_s_setprio(1);
    #pragma unroll
    for (int mi = 0; mi < 4; ++mi)
      #pragma unroll
      for (int ni = 0; ni < 4; ++ni)
        acc[mi][ni] = __builtin_amdgcn_mfma_f32_16x16x32_fp8_fp8(fa[mi].ll[1], fb[ni].ll[1], acc[mi][ni], 0, 0, 0);
    __builtin_amdgcn_s_setprio(0);
    __builtin_amdgcn_s_barrier();

    if (t + 2 < NT) stageA(t + 2, 1);
    __builtin_amdgcn_s_setprio(1);
    #pragma unroll
    for (int mi = 0; mi < 4; ++mi)
      #pragma unroll
      for (int ni = 0; ni < 4; ++ni)
        acc[mi + 4][ni] = __builtin_amdgcn_mfma_f32_16x16x32_fp8_fp8(fa[mi + 4].ll[1], fb[ni].ll[1], acc[mi + 4][ni], 0, 0, 0);
    __builtin_amdgcn_s_setprio(0);
    if (t + 2 < NT) { asm volatile("s_waitcnt vmcnt(4)" ::: "memory"); }
    else            { asm volatile("s_waitcnt vmcnt(0)" ::: "memory"); }
    __builtin_amdgcn_s_barrier();
  }
  asm volatile("s_waitcnt vmcnt(0)" ::: "memory");

  #pragma unroll
  for (int mi = 0; mi < 8; ++mi)
    #pragma unroll
    for (int ni = 0; ni < 4; ++ni)
      acc[mi][ni] *= 0.015625f;

  // EPI_GLU only in this kernel now
  #pragma unroll
  for (int mi = 0; mi < 8; ++mi)
    #pragma unroll
    for (int np = 0; np < 2; ++np)
      #pragma unroll
      for (int r = 0; r < 4; ++r) {
        int grow = m0 + wm * 128 + mi * 16 + lq * 4 + r;
        int gcol = (n0 >> 1) + wn * 32 + np * 16 + lc;
        float g = acc[mi][2 * np][r];
        float u = acc[mi][2 * np + 1][r];
        C8[perm8((size_t)grow * ldc + gcol)] = f2fp8(u * g / (1.0f + __expf(-g)));
      }
  (void)partials; (void)nch;
}

// ---------------------------------------------------------------------------
// 512x256 fp8 STATS GEMM: gemm8 quadrant schedule with M=512 (B staged by 8
// M-blocks instead of 16 -> 25% fewer staged bytes). 8 waves, wave grid 2x4,
// per-wave out 256x64 (acc[16][4]). LDS 2 x 48KB. Per-region staging ledger:
// B(t+2)@q1, A(t+2).{0,1}@q2, A(t+2).2@q3, A(t+2).3@next-tile-q0 (other buf).
// vmcnt(5) once per tile.
__launch_bounds__(512, 1)
__global__ void k_gemm10(const u8* __restrict__ A8, const u8* __restrict__ B8,
                         v4f* __restrict__ partials, int K, int nch) {
  __shared__ __align__(16) u8 lds8[98304];      // buf b at b*49152; A 32KB, B at +32768
  const int tid = threadIdx.x;
  const int lane = tid & 63, wid = tid >> 6;
  const int wm = wid >> 2, wn = wid & 3;        // wave grid 2x4; per-wave out 256x64
  const int lc = lane & 15, lq = lane >> 4;
  const int m0 = blockIdx.x * 512, n0 = blockIdx.y * 256;

  const u8* srcA[4]; const u8* srcB[2];
  #pragma unroll
  for (int i = 0; i < 4; ++i) {
    int ci = i * 512 + tid;
    int r = ci >> 2;
    int logc = (ci & 3) ^ ((r >> 1) & 3);
    srcA[i] = A8 + (size_t)(m0 + r) * K + logc * 16;
  }
  #pragma unroll
  for (int i = 0; i < 2; ++i) {
    int ci = i * 512 + tid;
    int r = ci >> 2;
    int logc = (ci & 3) ^ ((r >> 1) & 3);
    srcB[i] = B8 + (size_t)(n0 + r) * K + logc * 16;
  }

  v4f acc[16][4];
  #pragma unroll
  for (int i = 0; i < 16; ++i)
    #pragma unroll
    for (int j = 0; j < 4; ++j) acc[i][j] = (v4f){0.f, 0.f, 0.f, 0.f};

  const int csw = (lc >> 1) & 3;
  int aoff[16], boff[4];
  #pragma unroll
  for (int mi = 0; mi < 16; ++mi) aoff[mi] = (wm * 256 + mi * 16 + lc) * 64 + ((lq ^ csw) << 4);
  #pragma unroll
  for (int ni = 0; ni < 4; ++ni) boff[ni] = (wn * 64 + ni * 16 + lc) * 64 + ((lq ^ csw) << 4);

  auto stageA = [&](int t, int i) {
    gload16(&lds8[(t & 1) * 49152 + i * 8192 + wid * 1024], srcA[i] + t * 64);
  };
  auto stageB = [&](int t, int i) {
    gload16(&lds8[(t & 1) * 49152 + 32768 + i * 8192 + wid * 1024], srcB[i] + t * 64);
  };

  // prologue: tile0 full (6), tile1 minus A.3 (5); wait tile0 -> vmcnt(5)
  stageB(0, 0); stageB(0, 1); stageA(0, 0); stageA(0, 1); stageA(0, 2); stageA(0, 3);
  stageB(1, 0); stageB(1, 1); stageA(1, 0); stageA(1, 1); stageA(1, 2);
  asm volatile("s_waitcnt vmcnt(5)" ::: "memory");
  __builtin_amdgcn_s_barrier();

  union Frag { v4i v; long long ll[2]; };
  const int NT = K >> 6;
  for (int t = 0; t < NT; ++t) {
    const u8* Ab = &lds8[(t & 1) * 49152];
    const u8* Bb = Ab + 32768;
    Frag fa[4], fb[4];

    // q0: read fb + fa g0 (rows 0-127); stage A(t+1).3 (other buffer, dead)
    #pragma unroll
    for (int ni = 0; ni < 4; ++ni) fb[ni].v = *(const v4i*)(Bb + boff[ni]);
    #pragma unroll
    for (int j = 0; j < 4; ++j) fa[j].v = *(const v4i*)(Ab + aoff[j]);
    if (t + 1 < NT) stageA(t + 1, 3);
    asm volatile("s_waitcnt lgkmcnt(0)" ::: "memory");
    __builtin_amdgcn_sched_barrier(0);
    __builtin_amdgcn_s_setprio(1);
    #pragma unroll
    for (int j = 0; j < 4; ++j)
      #pragma unroll
      for (int ni = 0; ni < 4; ++ni) {
        acc[j][ni] = __builtin_amdgcn_mfma_f32_16x16x32_fp8_fp8(fa[j].ll[0], fb[ni].ll[0], acc[j][ni], 0, 0, 0);
        acc[j][ni] = __builtin_amdgcn_mfma_f32_16x16x32_fp8_fp8(fa[j].ll[1], fb[ni].ll[1], acc[j][ni], 0, 0, 0);
      }
    __builtin_amdgcn_s_setprio(0);
    __builtin_amdgcn_s_barrier();

    // q1: read fa g1 (rows 128-255); stage B(t+2) (B dead after q0 barrier)
    #pragma unroll
    for (int j = 0; j < 4; ++j) fa[j].v = *(const v4i*)(Ab + aoff[4 + j]);
    if (t + 2 < NT) { stageB(t + 2, 0); stageB(t + 2, 1); }
    asm volatile("s_waitcnt lgkmcnt(0)" ::: "memory");
    __builtin_amdgcn_sched_barrier(0);
    __builtin_amdgcn_s_setprio(1);
    #pragma unroll
    for (int j = 0; j < 4; ++j)
      #pragma unroll
      for (int ni = 0; ni < 4; ++ni) {
        acc[4 + j][ni] = __builtin_amdgcn_mfma_f32_16x16x32_fp8_fp8(fa[j].ll[0], fb[ni].ll[0], acc[4 + j][ni], 0, 0, 0);
        acc[4 + j][ni] = __builtin_amdgcn_mfma_f32_16x16x32_fp8_fp8(fa[j].ll[1], fb[ni].ll[1], acc[4 + j][ni], 0, 0, 0);
      }
    __builtin_amdgcn_s_setprio(0);
    __builtin_amdgcn_s_barrier();

    // q2: read fa g2 (rows 256-383); stage A(t+2).{0,1} (rows 0-255 dead)
    #pragma unroll
    for (int j = 0; j < 4; ++j) fa[j].v = *(const v4i*)(Ab + aoff[8 + j]);
    if (t + 2 < NT) { stageA(t + 2, 0); stageA(t + 2, 1); }
    asm volatile("s_waitcnt lgkmcnt(0)" ::: "memory");
    __builtin_amdgcn_sched_barrier(0);
    __builtin_amdgcn_s_setprio(1);
    #pragma unroll
    for (int j = 0; j < 4; ++j)
      #pragma unroll
      for (int ni = 0; ni < 4; ++ni) {
        acc[8 + j][ni] = __builtin_amdgcn_mfma_f32_16x16x32_fp8_fp8(fa[j].ll[0], fb[ni].ll[0], acc[8 + j][ni], 0, 0, 0);
        acc[8 + j][ni] = __builtin_amdgcn_mfma_f32_16x16x32_fp8_fp8(fa[j].ll[1], fb[ni].ll[1], acc[8 + j][ni], 0, 0, 0);
      }
    __builtin_amdgcn_s_setprio(0);
    __builtin_amdgcn_s_barrier();

    // q3: read fa g3 (rows 384-511); stage A(t+2).2 (rows 256-383 dead); vmcnt
    #pragma unroll
    for (int j = 0; j < 4; ++j) fa[j].v = *(const v4i*)(Ab + aoff[12 + j]);
    if (t + 2 < NT) stageA(t + 2, 2);
    asm volatile("s_waitcnt lgkmcnt(0)" ::: "memory");
    __builtin_amdgcn_sched_barrier(0);
    __builtin_amdgcn_s_setprio(1);
    #pragma unroll
    for (int j = 0; j < 4; ++j)
      #pragma unroll
      for (int ni = 0; ni < 4; ++ni) {
        acc[12 + j][ni] = __builtin_amdgcn_mfma_f32_16x16x32_fp8_fp8(fa[j].ll[0], fb[ni].ll[0], acc[12 + j][ni], 0, 0, 0);
        acc[12 + j][ni] = __builtin_amdgcn_mfma_f32_16x16x32_fp8_fp8(fa[j].ll[1], fb[ni].ll[1], acc[12 + j][ni], 0, 0, 0);
      }
    __builtin_amdgcn_s_setprio(0);
    if (t + 2 < NT) { asm volatile("s_waitcnt vmcnt(5)" ::: "memory"); }
    else            { asm volatile("s_waitcnt vmcnt(0)" ::: "memory"); }
    __builtin_amdgcn_s_barrier();
  }
  asm volatile("s_waitcnt vmcnt(0)" ::: "memory");

  // undo x64 weight scale
  #pragma unroll
  for (int mi = 0; mi < 16; ++mi)
    #pragma unroll
    for (int ni = 0; ni < 4; ++ni)
      acc[mi][ni] *= 0.015625f;

  // STATS epilogue (512 rows), scratch aliased onto dead staging LDS
  float* s_mx = (float*)lds8;                   // 8 KB
  float* s_sm = (float*)(lds8 + 8192);          // 8 KB
  int*   s_ax = (int*)(lds8 + 16384);           // 8 KB
  __syncthreads();
  #pragma unroll
  for (int mi = 0; mi < 16; ++mi) {
    #pragma unroll
    for (int r = 0; r < 4; ++r) {
      float v0 = acc[mi][0][r], v1 = acc[mi][1][r], v2 = acc[mi][2][r], v3 = acc[mi][3][r];
      float mx = v0; int ax = lc;
      if (v1 > mx) { mx = v1; ax = 16 + lc; }
      if (v2 > mx) { mx = v2; ax = 32 + lc; }
      if (v3 > mx) { mx = v3; ax = 48 + lc; }
      #pragma unroll
      for (int off = 1; off < 16; off <<= 1) {
        float om = __shfl_xor(mx, off); int oa = __shfl_xor(ax, off);
        if (om > mx || (om == mx && oa < ax)) { mx = om; ax = oa; }
      }
      float se = __expf(v0 - mx) + __expf(v1 - mx) + __expf(v2 - mx) + __expf(v3 - mx);
      #pragma unroll
      for (int off = 1; off < 16; off <<= 1) se += __shfl_xor(se, off);
      if (lc == 0) {
        int row = wm * 256 + mi * 16 + lq * 4 + r;
        s_mx[row * 4 + wn] = mx; s_sm[row * 4 + wn] = se; s_ax[row * 4 + wn] = wn * 64 + ax;
      }
    }
  }
  __syncthreads();
  {
    float gm = s_mx[tid * 4]; int ga = s_ax[tid * 4];
    #pragma unroll
    for (int w = 1; w < 4; ++w) {
      float m = s_mx[tid * 4 + w];
      if (m > gm) { gm = m; ga = s_ax[tid * 4 + w]; }
    }
    float gs = 0.f;
    #pragma unroll
    for (int w = 0; w < 4; ++w) gs += s_sm[tid * 4 + w] * __expf(s_mx[tid * 4 + w] - gm);
    v4f rec; rec[0] = gm; rec[1] = gs; rec[2] = __int_as_float(n0 + ga); rec[3] = 0.f;
    partials[(size_t)(m0 + tid) * nch + blockIdx.y] = rec;
  }
}

// ---------------------------------------------------------------------------
// PIPELINED 128x128 GEMM fp8 e4m3: BK=64B, 4 waves, 32KB dbuf LDS (4 blk/CU),
// counted vmcnt(4). acc scaled by 1/64 (B weights pre-x64).
template <int EPI>
__launch_bounds__(256, 4)
__global__ void k_gemm9(const u8* __restrict__ A8, const u8* __restrict__ B8,
                        u16* __restrict__ Cbf, float* __restrict__ Cf32,
                        const int* __restrict__ keepArr, RmsSrc rs,
                        int K, int ldb, int ldc) {
  __shared__ __align__(16) u8 lds8[32768];
  const int tid = threadIdx.x;
  const int lane = tid & 63, wid = tid >> 6;
  const int wm = wid >> 1, wn = wid & 1;
  const int lc = lane & 15, lq = lane >> 4;
  const int m0 = blockIdx.x * 128, n0 = blockIdx.y * 128;

  const u8* srcA[2]; const u8* srcB[2];
  #pragma unroll
  for (int i = 0; i < 2; ++i) {
    int ci = i * 256 + tid;
    int r = ci >> 2;
    int logc = (ci & 3) ^ ((r >> 1) & 3);
    srcA[i] = A8 + (size_t)(m0 + r) * K + logc * 16;
    srcB[i] = B8 + (size_t)(n0 + r) * ldb + logc * 16;
  }

  v4f acc[4][4];
  #pragma unroll
  for (int i = 0; i < 4; ++i)
    #pragma unroll
    for (int j = 0; j < 4; ++j) acc[i][j] = (v4f){0.f, 0.f, 0.f, 0.f};

  const int csw = (lc >> 1) & 3;
  int aoff[4], boff[4];
  #pragma unroll
  for (int mi = 0; mi < 4; ++mi) aoff[mi] = (wm * 64 + mi * 16 + lc) * 64 + ((lq ^ csw) << 4);
  #pragma unroll
  for (int ni = 0; ni < 4; ++ni) boff[ni] = (wn * 64 + ni * 16 + lc) * 64 + ((lq ^ csw) << 4);

  auto stageTo = [&](int b, int t) {
    #pragma unroll
    for (int i = 0; i < 2; ++i) {
      gload16(&lds8[b * 16384 + i * 4096 + wid * 1024], srcA[i] + t * 64);
      gload16(&lds8[b * 16384 + 8192 + i * 4096 + wid * 1024], srcB[i] + t * 64);
    }
  };

  stageTo(0, 0);
  union Frag { v4i v; long long ll[2]; };
  const int NT = K >> 6;
  for (int t = 0; t < NT; ++t) {
    const int cur = t & 1;
    if (t + 1 < NT) {
      stageTo(cur ^ 1, t + 1);
      asm volatile("s_waitcnt vmcnt(4)" ::: "memory");
    } else {
      asm volatile("s_waitcnt vmcnt(0)" ::: "memory");
    }
    __builtin_amdgcn_s_barrier();
    const u8* Ab = &lds8[cur * 16384];
    const u8* Bb = Ab + 8192;
    Frag fa[4], fb[4];
    #pragma unroll
    for (int mi = 0; mi < 4; ++mi) fa[mi].v = *(const v4i*)(Ab + aoff[mi]);
    #pragma unroll
    for (int ni = 0; ni < 4; ++ni) fb[ni].v = *(const v4i*)(Bb + boff[ni]);
    __builtin_amdgcn_s_setprio(1);
    #pragma unroll
    for (int mi = 0; mi < 4; ++mi)
      #pragma unroll
      for (int ni = 0; ni < 4; ++ni)
        acc[mi][ni] = __builtin_amdgcn_mfma_f32_16x16x32_fp8_fp8(fa[mi].ll[0], fb[ni].ll[0], acc[mi][ni], 0, 0, 0);
    __builtin_amdgcn_s_setprio(0);
    asm volatile("s_waitcnt lgkmcnt(0)" ::: "memory");
    __builtin_amdgcn_sched_barrier(0);
    __builtin_amdgcn_s_barrier();
    __builtin_amdgcn_s_setprio(1);
    #pragma unroll
    for (int mi = 0; mi < 4; ++mi)
      #pragma unroll
      for (int ni = 0; ni < 4; ++ni)
        acc[mi][ni] = __builtin_amdgcn_mfma_f32_16x16x32_fp8_fp8(fa[mi].ll[1], fb[ni].ll[1], acc[mi][ni], 0, 0, 0);
    __builtin_amdgcn_s_setprio(0);
  }

  #pragma unroll
  for (int mi = 0; mi < 4; ++mi)
    #pragma unroll
    for (int ni = 0; ni < 4; ++ni)
      #pragma unroll
      for (int r = 0; r < 4; ++r) {
        int grow = m0 + wm * 64 + mi * 16 + lq * 4 + r;
        int gcol = n0 + wn * 64 + ni * 16 + lc;
        size_t idx = (size_t)grow * ldc + gcol;
        float vv = acc[mi][ni][r] * 0.015625f;
        if constexpr (EPI == EPI_BF16) {
          Cbf[idx] = f2bf(vv);
        } else if constexpr (EPI == EPI_OEMB) {
          int t_ = grow & 15, bn = grow >> 4;
          int tok = (t_ == 0) ? rs.ftok[bn] : cMASK;
          float kf = (float)keepArr[bn];
          Cf32[idx] = rs.emb[(size_t)tok * cD + gcol] + vv * kf;
        } else {  // EPI_DOWNACC
          Cf32[idx] += vv;
        }
      }
}

// ---------------------------------------------------------------------------
__global__ void k_rope(u16* __restrict__ qb, u16* __restrict__ kb,
                       const int* __restrict__ anchors, const int* __restrict__ cpos) {
  int r = blockIdx.x;
  int which = (r >= MKV);
  int rr = which ? r - MKV : r;
  int j = rr % 17, bn = rr / 17;
  if (!which && j == 0) return;
  u16* buf = which ? kb : qb;
  int pos = (which && j == 0) ? cpos[bn] : (anchors[bn] + j - 1);
  float fp = (float)pos;
  for (int p = threadIdx.x; p < cH * 64; p += 256) {
    int h = p >> 6, i = p & 63;
    size_t base = (size_t)rr * cD + h * cHD;
    float x1 = bf2f(buf[base + i]);
    float x2 = bf2f(buf[base + 64 + i]);
    float freq = powf(10000.0f, -((float)(2 * i)) / 128.0f);
    float ang = fp * freq;
    float sn = sinf(ang), cn = cosf(ang);
    buf[base + i]      = f2bf(x1 * cn - x2 * sn);
    buf[base + 64 + i] = f2bf(x2 * cn + x1 * sn);
  }
}

// Attention. Writes attn-out compact fp8 perm8 (token rows).
__global__ void k_attn(u16* __restrict__ qb, const u16* __restrict__ kb,
                       const u16* __restrict__ vb, u8* __restrict__ ao8) {
  int blk = blockIdx.x;
  int h = blk % cH, bn = blk / cH;
  __shared__ float qs[16][128], ks[17][128], vs[17][128], ps[16][18];
  int lane = threadIdx.x;
  for (int e = lane; e < 16 * 128; e += 64) {
    int r = e >> 7, d = e & 127;
    qs[r][d] = bf2f(qb[((size_t)(bn * 17 + 1 + r)) * cD + h * cHD + d]);
  }
  for (int e = lane; e < 17 * 128; e += 64) {
    int r = e >> 7, d = e & 127;
    ks[r][d] = bf2f(kb[((size_t)(bn * 17 + r)) * cD + h * cHD + d]);
    vs[r][d] = bf2f(vb[((size_t)(bn * 17 + r)) * cD + h * cHD + d]);
  }
  __syncthreads();
  for (int e = lane; e < 16 * 17; e += 64) {
    int qi = e / 17, ki = e % 17;
    float s = 0.f;
    for (int d = 0; d < 128; ++d) s += qs[qi][d] * ks[ki][d];
    ps[qi][ki] = s * 0.08838834764831845f;
  }
  __syncthreads();
  if (lane < 16) {
    float m = -3e38f;
    for (int kk = 0; kk < 17; ++kk) m = fmaxf(m, ps[lane][kk]);
    float s = 0.f;
    for (int kk = 0; kk < 17; ++kk) { float e_ = __expf(ps[lane][kk] - m); ps[lane][kk] = e_; s += e_; }
    float is = 1.0f / s;
    for (int kk = 0; kk < 17; ++kk) ps[lane][kk] *= is;
  }
  __syncthreads();
  for (int e = lane; e < 16 * 128; e += 64) {
    int qi = e >> 7, d = e & 127;
    float s = 0.f;
    for (int kk = 0; kk < 17; ++kk) s += ps[qi][kk] * vs[kk][d];
    ao8[perm8((size_t)(bn * 16 + qi) * cD + h * cHD + d)] = f2fp8(s);
  }
}

__global__ void k_tgt(const u16* __restrict__ hout, const float* __restrict__ Wlm,
                      const int* __restrict__ ids, const int* __restrict__ anchors,
                      int* __restrict__ tgt_tok, float* __restrict__ tgt_logit) {
  int w = threadIdx.x >> 6, lane = threadIdx.x & 63;
  int m = blockIdx.x * 4 + w;
  int bn = m >> 4, t = m & 15, b = bn / cNA;
  int label = anchors[bn] + t;
  int sl = (label < cS - 1) ? label : (cS - 1);
  int tok = ids[(size_t)b * cS + sl];
  const u16* hr = hout + (size_t)m * cD;
  const float* wr = Wlm + (size_t)tok * cD;
  float s = 0.f;
  for (int d = lane; d < cD; d += 64) s += bf2f(hr[d]) * wr[d];
  s = waveSum(s);
  if (lane == 0) { tgt_tok[m] = tok; tgt_logit[m] = s; }
}

__global__ void k_combine(const v4f* __restrict__ partials, const int* __restrict__ tgt_tok,
                          const float* __restrict__ tgt_logit, const int* __restrict__ keepArr,
                          const int* __restrict__ anchors, const float* __restrict__ lmask,
                          float* __restrict__ tokOut, int nch) {
  int m = blockIdx.x;
  int tid = threadIdx.x, lane = tid & 63, w = tid >> 6;
  float cm = -3.0e38f, cs = 0.f; int ca = 0x7fffffff;
  if (tid < nch) {
    v4f rec = partials[(size_t)m * nch + tid];
    cm = rec[0]; cs = rec[1]; ca = __float_as_int(rec[2]);
  }
  float gm = cm; int ga = ca;
  #pragma unroll
  for (int off = 1; off < 64; off <<= 1) {
    float om = __shfl_xor(gm, off); int oa = __shfl_xor(ga, off);
    if (om > gm || (om == gm && oa < ga)) { gm = om; ga = oa; }
  }
  __shared__ float wmx[4]; __shared__ int wax[4]; __shared__ float wsm[4];
  if (lane == 0) { wmx[w] = gm; wax[w] = ga; }
  __syncthreads();
  if (tid == 0) {
    for (int i = 1; i < 4; ++i)
      if (wmx[i] > wmx[0] || (wmx[i] == wmx[0] && wax[i] < wax[0])) { wmx[0] = wmx[i]; wax[0] = wax[i]; }
  }
  __syncthreads();
  gm = wmx[0]; ga = wax[0];
  float s = (tid < nch) ? cs * __expf(cm - gm) : 0.f;
  s = waveSum(s);
  if (lane == 0) wsm[w] = s;
  __syncthreads();
  if (tid == 0) {
    float gs = wsm[0] + wsm[1] + wsm[2] + wsm[3];
    float logZ = gm + logf(gs);
    int bn = m >> 4, t = m & 15, b = bn / cNA;
    int label = anchors[bn] + t;
    int sl = (label < cS - 1) ? label : (cS - 1);
    float wgt = (float)keepArr[bn] * ((t > 0) ? 1.f : 0.f) * ((label < cS) ? 1.f : 0.f) *
                lmask[(size_t)b * cS + sl];
    float lp = tgt_logit[m] - logZ;
    int tg = tgt_tok[m];
    tokOut[m * 4 + 0] = lp * wgt;
    tokOut[m * 4 + 1] = wgt;
    tokOut[m * 4 + 2] = ((ga == tg) && (wgt > 0.5f)) ? 1.f : 0.f;
    tokOut[m * 4 + 3] = 0.f;
  }
}

__global__ void k_final(const float* __restrict__ tokOut, float* __restrict__ outp) {
  int tid = threadIdx.x;
  float swl = 0.f, sw = 0.f, sm = 0.f;
  for (int m = tid; m < MTOK; m += 256) {
    swl += tokOut[m * 4 + 0];
    sw  += tokOut[m * 4 + 1];
    sm  += tokOut[m * 4 + 2];
  }
  swl = waveSum(swl); sw = waveSum(sw); sm = waveSum(sm);
  __shared__ float r0[4], r1[4], r2[4];
  int lane = tid & 63, w = tid >> 6;
  if (lane == 0) { r0[w] = swl; r1[w] = sw; r2[w] = sm; }
  __syncthreads();
  if (tid == 0) {
    float a = r0[0] + r0[1] + r0[2] + r0[3];
    float b = r1[0] + r1[1] + r1[2] + r1[3];
    float c = r2[0] + r2[1] + r2[2] + r2[3];
    float denom = b + 1e-6f;
    float loss = -a / denom;
    float acc  = c / denom;
    if (b == 0.0f) loss = -300.0f;
    outp[0] = loss;
    outp[1] = acc;
  }
}

__global__ void k_sentinel(float* outp) {
  if (threadIdx.x == 0) { outp[0] = -777.0f; outp[1] = -777.0f; }
}

// ---------------------------------------------------------------------------
extern "C" void kernel_launch(void* const* d_in, const int* in_sizes, int n_in,
                              void* d_out, int out_size, void* d_ws, size_t ws_size,
                              hipStream_t stream) {
  const int*   ids   = (const int*)  d_in[0];
  const float* hs    = (const float*)d_in[1];
  const float* lmask = (const float*)d_in[2];
  const float* rv    = (const float*)d_in[3];
  const float* emb   = (const float*)d_in[4];
  const float* wlm   = (const float*)d_in[5];
  const float* wq    = (const float*)d_in[6];
  const float* wk    = (const float*)d_in[7];
  const float* wv    = (const float*)d_in[8];
  const float* wo    = (const float*)d_in[9];
  const float* wg    = (const float*)d_in[10];
  const float* wu    = (const float*)d_in[11];
  const float* wd    = (const float*)d_in[12];
  const float* nattn = (const float*)d_in[13];
  const float* nmlp  = (const float*)d_in[14];
  const float* nout  = (const float*)d_in[15];
  const float* nchs  = (const float*)d_in[16];
  (void)in_sizes; (void)n_in; (void)out_size;

  float* outp = (float*)d_out;

  char* wsb = (char*)d_ws;
  size_t off = 0;
  auto alloc = [&](size_t bytes) -> void* {
    void* p = wsb + off;
    off = (off + bytes + 255) & ~(size_t)255;
    return p;
  };
  int*   anchors = (int*)  alloc((size_t)cB * cNA * 4);
  int*   keepA   = (int*)  alloc((size_t)cB * cNA * 4);
  int*   ftok    = (int*)  alloc((size_t)cB * cNA * 4);
  int*   cpos    = (int*)  alloc((size_t)cB * cNA * 4);
  int*   self    = (int*)  alloc((size_t)cB * NCAND * 4);
  float* rowinv  = (float*)alloc((size_t)MKV * 4);
  int*   ttok    = (int*)  alloc((size_t)MTOK * 4);
  float* tlogit  = (float*)alloc((size_t)MTOK * 4);
  float* tokOut  = (float*)alloc((size_t)MTOK * 4 * 4);

  const size_t szQ  = (size_t)MKV * cD * 2;           // 17.8 MB (q -> h -> h_out)
  const size_t szX  = (size_t)MTOK * cD * 4;          // 33.6 MB (fp32 residual)
  u16* qb = (u16*)alloc(szQ);
  const size_t a1off = off;

  RmsSrc rs{hs, emb, nattn, nchs, rowinv, ftok, cpos};

  // common head
  k_select <<<dim3(cB * 16), 256, 0, stream>>>(lmask, rv, self);
  k_anchors<<<dim3(cB),      256, 0, stream>>>(lmask, self, ids, anchors, keepA, ftok, cpos);

  // ---------------- fast tier
  size_t kvb_off  = a1off;                            // kv8 fp8: 8.9 MB
  size_t a1f_off  = (kvb_off + szQ + 255) & ~(size_t)255;
  size_t a1f_sz   = 2 * szQ > (szX + (size_t)MTOK * 4096 * 2) ? 2 * szQ
                                                             : (szX + (size_t)MTOK * 4096 * 2);
  size_t wreg_off = (a1f_off + a1f_sz + 255) & ~(size_t)255;
  size_t wreg_sz  = (size_t)cV * cD * 2;              // 131 MB (largest stage)
  size_t need_fast = wreg_off + wreg_sz;

  if (need_fast <= ws_size) {
    u8*    kv8   = (u8*)(wsb + kvb_off);
    u16*   kb    = (u16*)(wsb + a1f_off);
    u16*   vb    = (u16*)(wsb + a1f_off + szQ);
    float* xb    = (float*)(wsb + a1f_off);
    u8*    ao8   = (u8*)(wsb + a1f_off + 2 * szQ);
    u8*    cbuf8 = (u8*)(wsb + a1f_off + 2 * szQ + (size_t)MTOK * cD);
    v4f*   parts = (v4f*)(wsb + a1f_off);             // lm-head stage (xb dead)
    u8*    h8    = (u8*)(wsb + a1f_off + (size_t)16 * 1024 * 1024);
    u16*   hb    = qb;
    u16*   houtb = qb;
    u16*   wT    = (u16*)(wsb + wreg_off);
    const size_t szDD = (size_t)cD * cD;
    u8* wq8 = (u8*)wT;        u8* wk8 = wq8 + szDD;
    u8* wv8 = wq8 + 2 * szDD; u8* wo8 = wq8 + 3 * szDD;
    const size_t szDF = (size_t)cD * cDFF;
    u8* wgu8 = (u8*)wT;                               // stage 2: 33.5 MB
    u8* wd8  = (u8*)wT + 2 * szDF;
    u8* h8m  = (u8*)wT + 3 * szDF;
    u8* wlm8 = (u8*)wT;                               // stage 3: 65.5 MB

    k_build2<<<dim3(MKV), 256, 0, stream>>>(hs, emb, nattn, nchs, ftok, cpos, kv8);

    k_tconv8<<<dim3(32, 32), 256, 0, stream>>>(wq, wq8, cD, cD, -1, 64.0f);
    k_tconv8<<<dim3(32, 32), 256, 0, stream>>>(wk, wk8, cD, cD, -1, 64.0f);
    k_tconv8<<<dim3(32, 32), 256, 0, stream>>>(wv, wv8, cD, cD, -1, 64.0f);
    k_tconv8<<<dim3(32, 32), 256, 0, stream>>>(wo, wo8, cD, cD, -1, 64.0f);

    k_gemm9<EPI_BF16><<<dim3(MKV / 128, cD / 128), 256, 0, stream>>>(
        kv8, wq8, qb, nullptr, nullptr, rs, cD, cD, cD);
    k_gemm9<EPI_BF16><<<dim3(MKV / 128, cD / 128), 256, 0, stream>>>(
        kv8, wk8, kb, nullptr, nullptr, rs, cD, cD, cD);
    k_gemm9<EPI_BF16><<<dim3(MKV / 128, cD / 128), 256, 0, stream>>>(
        kv8, wv8, vb, nullptr, nullptr, rs, cD, cD, cD);

    k_rope<<<dim3(2 * MKV), 256, 0, stream>>>(qb, kb, anchors, cpos);
    k_attn<<<dim3(cB * cNA * cH), 64, 0, stream>>>(qb, kb, vb, ao8);

    k_gemm9<EPI_OEMB><<<dim3(MTOK / 128, cD / 128), 256, 0, stream>>>(
        ao8, wo8, nullptr, xb, keepA, rs, cD, cD, cD);

    k_rms<<<dim3(MTOK), 256, 0, stream>>>(xb, nmlp, hb);
    k_cvt8<<<dim3(1024), 256, 0, stream>>>(hb, h8m, (long)MTOK * cD);

    k_tconv8<<<dim3(128, 32), 256, 0, stream>>>(wg, wgu8, cD, cDFF, 0, 64.0f);
    k_tconv8<<<dim3(128, 32), 256, 0, stream>>>(wu, wgu8, cD, cDFF, 16, 64.0f);
    k_tconv8<<<dim3(32, 128), 256, 0, stream>>>(wd, wd8, cDFF, cD, -1, 64.0f);

    for (int cb = 0; cb < cDFF; cb += 4096) {
      k_gemm8<EPI_GLU><<<dim3(MTOK / 256, 32), 512, 0, stream>>>(
          h8m, wgu8 + (size_t)cb * 2 * cD, cbuf8, nullptr, cD, 4096, 0);
      k_gemm9<EPI_DOWNACC><<<dim3(MTOK / 128, cD / 128), 256, 0, stream>>>(
          cbuf8, wd8 + cb, nullptr, xb, nullptr, rs, 4096, cDFF, cD);
    }

    k_rms<<<dim3(MTOK), 256, 0, stream>>>(xb, nout, houtb);

    k_tgt<<<dim3(MTOK / 4), 256, 0, stream>>>(houtb, wlm, ids, anchors, ttok, tlogit);

    k_cvt8 <<<dim3(1024), 256, 0, stream>>>(houtb, h8, (long)MTOK * cD);
    k_conv8<<<dim3(2048), 256, 0, stream>>>(wlm, wlm8, (long)cV * cD, 64.0f);
    k_gemm10<<<dim3(MTOK / 512, NCH2), 512, 0, stream>>>(h8, wlm8, parts, cD, NCH2);

    k_combine<<<dim3(MTOK), 256, 0, stream>>>(parts, ttok, tlogit, keepA, anchors, lmask, tokOut, NCH2);
    k_final  <<<dim3(1), 256, 0, stream>>>(tokOut, outp);
    return;
  }

  // ---------------- fallback: signal insufficient workspace
  k_sentinel<<<dim3(1), 64, 0, stream>>>(outp);
}

// Round 17
// 1434.721 us; speedup vs baseline: 1.6945x; 1.6945x over previous
//
#include <hip/hip_runtime.h>
#include <math.h>

typedef unsigned short u16;
typedef unsigned char u8;
typedef short v8s __attribute__((ext_vector_type(8)));
typedef u16   v4u __attribute__((ext_vector_type(4)));
typedef float v4f __attribute__((ext_vector_type(4)));
typedef int   v2i __attribute__((ext_vector_type(2)));
typedef int   v4i __attribute__((ext_vector_type(4)));

#define DEVFN static __device__ __forceinline__

constexpr int cB = 2, cS = 4096, cD = 2048, cV = 32000, cH = 16, cHD = 128;
constexpr int cBS = 16, cNA = 128, cMASK = 31999, cDFF = 8192;
constexpr int NCAND = cS - cBS + 1;   // 4081 anchor candidates
constexpr int MTOK  = cB * cNA * cBS; // 4096 query tokens
constexpr int MKV   = cB * cNA * 17;  // 4352 kv rows (ctx + 16)
constexpr int NCH2  = cV / 256;       // 125 vocab chunks (256-wide)

constexpr int EPI_BF16 = 0, EPI_OEMB = 2, EPI_DOWNACC = 3, EPI_STATS = 4, EPI_GLU = 5;

struct RmsSrc {
  const float* hs; const float* emb; const float* nattn; const float* nchs;
  const float* rowinv; const int* ftok; const int* cpos;
};

DEVFN u16 f2bf(float f) {               // RNE fp32 -> bf16
  union { float f; unsigned u; } a; a.f = f;
  unsigned u = a.u;
  u = u + 0x7fffu + ((u >> 16) & 1u);
  return (u16)(u >> 16);
}
DEVFN float bf2f(u16 h) {
  union { unsigned u; float f; } a; a.u = ((unsigned)h) << 16;
  return a.f;
}
DEVFN float waveSum(float v) {
  #pragma unroll
  for (int o = 32; o >= 1; o >>= 1) v += __shfl_xor(v, o);
  return v;
}
DEVFN void gload16(void* lds, const void* g) {
  __builtin_amdgcn_global_load_lds(
      (const __attribute__((address_space(1))) unsigned*)g,
      (__attribute__((address_space(3))) unsigned*)lds, 16, 0, 0);
}
DEVFN int pack4fp8(float a, float b, float c, float d) {
  int p = __builtin_amdgcn_cvt_pk_fp8_f32(a, b, 0, 0);
  p = __builtin_amdgcn_cvt_pk_fp8_f32(c, d, p, 1);
  return p;
}
DEVFN u8 f2fp8(float v) {
  return (u8)(__builtin_amdgcn_cvt_pk_fp8_f32(v, 0.f, 0, 0) & 0xff);
}
// permuted output offset for fp8 buffers: within each 64B K-group,
// newpos = lq*16 + kh*8 + j  for k = kh*32 + lq*8 + j
DEVFN long perm8(long i) {
  return (i & ~63L) | (((i >> 3) & 3) << 4) | (((i >> 5) & 1) << 3);
}

// ---------------------------------------------------------------------------
__global__ void k_select(const float* __restrict__ lmask, const float* __restrict__ rv_in,
                         int* __restrict__ self) {
  int b = blockIdx.x >> 4, chunk = blockIdx.x & 15;
  __shared__ float rvs[4096];
  for (int i = threadIdx.x; i < NCAND; i += 256) {
    bool valid = lmask[(size_t)b * cS + i] > 0.5f;
    rvs[i] = valid ? rv_in[(size_t)b * NCAND + i] : 2.0f;
  }
  __syncthreads();
  int i = chunk * 256 + threadIdx.x;
  if (i < NCAND) {
    float v = rvs[i];
    int rank = 0;
    for (int j = 0; j < NCAND; ++j) {
      float u = rvs[j];
      rank += (u < v) || (u == v && j < i);
    }
    self[(size_t)b * NCAND + i] = (rank < cNA) ? 1 : 0;
  }
}

__global__ void k_anchors(const float* __restrict__ lmask, const int* __restrict__ self,
                          const int* __restrict__ ids, int* __restrict__ anchors,
                          int* __restrict__ keepA, int* __restrict__ ftok, int* __restrict__ cpos) {
  int b = blockIdx.x;
  __shared__ int flags[4096];
  __shared__ int ssum[256];
  __shared__ int soff[257];
  __shared__ int abuf[cNA];
  for (int i = threadIdx.x; i < 4096; i += 256)
    flags[i] = (i < NCAND) ? (self[(size_t)b * NCAND + i] && (lmask[(size_t)b * cS + i] > 0.5f)) : 0;
  if (threadIdx.x < cNA) abuf[threadIdx.x] = 0;
  __syncthreads();
  int s = 0;
  #pragma unroll
  for (int j = 0; j < 16; ++j) s += flags[threadIdx.x * 16 + j];
  ssum[threadIdx.x] = s;
  __syncthreads();
  if (threadIdx.x == 0) {
    int a = 0;
    for (int t = 0; t < 256; ++t) { soff[t] = a; a += ssum[t]; }
    soff[256] = a;
  }
  __syncthreads();
  int nsel = soff[256];
  int p = soff[threadIdx.x];
  for (int j = 0; j < 16; ++j) {
    int i = threadIdx.x * 16 + j;
    if (flags[i]) { if (p < cNA) abuf[p] = i; ++p; }
  }
  __syncthreads();
  if (threadIdx.x < cNA) {
    int q = threadIdx.x;
    int kp = (q < nsel) ? 1 : 0;
    int a = kp ? abuf[q] : 0;
    anchors[b * cNA + q] = a;
    keepA[b * cNA + q] = kp;
    int av = a; if (av < 0) av = 0; if (av > cS - 1) av = cS - 1;
    int tok = ids[(size_t)b * cS + av];
    ftok[b * cNA + q] = kp ? tok : cMASK;
    cpos[b * cNA + q] = (a - 1 > 0) ? (a - 1) : 0;
  }
}

// kv_in = rms'd rows, materialized fp8 perm8. grid: MKV x 256
__global__ void k_build2(const float* __restrict__ hs, const float* __restrict__ emb,
                         const float* __restrict__ nattn, const float* __restrict__ nchs,
                         const int* __restrict__ ftok, const int* __restrict__ cpos,
                         u8* __restrict__ kv8) {
  int r = blockIdx.x;
  int j = r % 17, bn = r / 17, b = bn >> 7;
  const float* src; const float* w;
  if (j == 0) { src = hs + ((size_t)b * cS + cpos[bn]) * cD; w = nchs; }
  else {
    int tok = (j == 1) ? ftok[bn] : cMASK;
    src = emb + (size_t)tok * cD; w = nattn;
  }
  float ss = 0.f;
  for (int d = threadIdx.x; d < cD; d += 256) { float v = src[d]; ss += v * v; }
  ss = waveSum(ss);
  __shared__ float red[4];
  if ((threadIdx.x & 63) == 0) red[threadIdx.x >> 6] = ss;
  __syncthreads();
  float tot = red[0] + red[1] + red[2] + red[3];
  float inv = 1.0f / sqrtf(tot / cD + 1e-6f);
  for (int d = threadIdx.x; d < cD; d += 256)
    kv8[perm8((size_t)r * cD + d)] = f2fp8(src[d] * inv * w[d]);
}

// RMS over fp32 rows -> bf16
__global__ void k_rms(const float* __restrict__ xin, const float* __restrict__ w,
                      u16* __restrict__ outp) {
  int m = blockIdx.x;
  const float* row = xin + (size_t)m * cD;
  float ss = 0.f;
  for (int d = threadIdx.x; d < cD; d += 256) { float v = row[d]; ss += v * v; }
  ss = waveSum(ss);
  __shared__ float red[4];
  if ((threadIdx.x & 63) == 0) red[threadIdx.x >> 6] = ss;
  __syncthreads();
  float tot = red[0] + red[1] + red[2] + red[3];
  float inv = 1.0f / sqrtf(tot / cD + 1e-6f);
  for (int d = threadIdx.x; d < cD; d += 256)
    outp[(size_t)m * cD + d] = f2bf(row[d] * inv * w[d]);
}

// fp32 -> fp8 e4m3 with scale, PERMUTED 64B-group layout. 8 elems/thread
__global__ void k_conv8(const float* __restrict__ in, u8* __restrict__ out, long n, float scale) {
  long i = ((long)blockIdx.x * 256 + threadIdx.x) * 8;
  long stride = (long)gridDim.x * 256 * 8;
  for (; i < n; i += stride) {
    v4f a = *(const v4f*)(in + i), b = *(const v4f*)(in + i + 4);
    v2i pk;
    pk[0] = pack4fp8(a[0] * scale, a[1] * scale, a[2] * scale, a[3] * scale);
    pk[1] = pack4fp8(b[0] * scale, b[1] * scale, b[2] * scale, b[3] * scale);
    *(v2i*)(out + perm8(i)) = pk;
  }
}

// bf16 -> fp8 e4m3, PERMUTED 64B-group layout. 8 elems/thread
__global__ void k_cvt8(const u16* __restrict__ in, u8* __restrict__ out, long n) {
  long i = ((long)blockIdx.x * 256 + threadIdx.x) * 8;
  long stride = (long)gridDim.x * 256 * 8;
  for (; i < n; i += stride) {
    v8s a = *(const v8s*)(in + i);
    v2i pk;
    pk[0] = pack4fp8(bf2f((u16)a[0]), bf2f((u16)a[1]), bf2f((u16)a[2]), bf2f((u16)a[3]));
    pk[1] = pack4fp8(bf2f((u16)a[4]), bf2f((u16)a[5]), bf2f((u16)a[6]), bf2f((u16)a[7]));
    *(v2i*)(out + perm8(i)) = pk;
  }
}

// transpose + fp8(scale) + perm8; goff>=0: gate/up interleave (col j -> row
// (j>>4)*32+goff+(j&15)); goff<0: plain (row = col j)
__global__ void k_tconv8(const float* __restrict__ W, u8* __restrict__ WT8,
                         int K, int N, int goff, float scale) {
  __shared__ float tf[64][65];
  int n0 = blockIdx.x * 64, k0 = blockIdx.y * 64;
  int tid = threadIdx.x;
  int c4 = (tid & 15) * 4, r0 = tid >> 4;
  #pragma unroll
  for (int rr = 0; rr < 64; rr += 16) {
    int k = r0 + rr;
    v4f v = *(const v4f*)(W + (size_t)(k0 + k) * N + n0 + c4);
    #pragma unroll
    for (int e = 0; e < 4; ++e) tf[c4 + e][k] = v[e];
  }
  __syncthreads();
  int n = tid >> 2, kq = (tid & 3) * 16;
  int gn = n0 + n;
  size_t rout = (goff >= 0) ? (((size_t)(gn >> 4) << 5) + goff + (gn & 15)) : (size_t)gn;
  long base = (long)rout * K + k0 + kq;
  v2i p0, p1;
  p0[0] = pack4fp8(tf[n][kq + 0] * scale, tf[n][kq + 1] * scale, tf[n][kq + 2] * scale, tf[n][kq + 3] * scale);
  p0[1] = pack4fp8(tf[n][kq + 4] * scale, tf[n][kq + 5] * scale, tf[n][kq + 6] * scale, tf[n][kq + 7] * scale);
  p1[0] = pack4fp8(tf[n][kq + 8] * scale, tf[n][kq + 9] * scale, tf[n][kq + 10] * scale, tf[n][kq + 11] * scale);
  p1[1] = pack4fp8(tf[n][kq + 12] * scale, tf[n][kq + 13] * scale, tf[n][kq + 14] * scale, tf[n][kq + 15] * scale);
  *(v2i*)(WT8 + perm8(base)) = p0;
  *(v2i*)(WT8 + perm8(base + 8)) = p1;
}

// ---------------------------------------------------------------------------
// 8-PHASE PIPELINED 256x256 GEMM fp8 e4m3 (round-12 verified double-buffer
// form): b128 fragment reads, 64KB LDS (2 blk/CU), t+2 lookahead, vmcnt(4).
// EPI_STATS: softmax partials (logits = acc/64). EPI_GLU: interleaved gate/up,
// out fp8 perm8 = up * silu(gate) (weights pre-scaled x64 -> acc/64).
template <int EPI>
__launch_bounds__(512, 2)
__global__ void k_gemm8(const u8* __restrict__ A8, const u8* __restrict__ B8,
                        u8* __restrict__ C8, v4f* __restrict__ partials,
                        int K, int ldc, int nch) {
  __shared__ __align__(16) u8 lds8[65536];
  const int tid = threadIdx.x;
  const int lane = tid & 63, wid = tid >> 6;
  const int wm = wid >> 2, wn = wid & 3;        // per-wave out 128x64
  const int lc = lane & 15, lq = lane >> 4;
  const int m0 = blockIdx.x * 256, n0 = blockIdx.y * 256;

  const u8* srcA[2]; const u8* srcB[2];
  #pragma unroll
  for (int i = 0; i < 2; ++i) {
    int ci = i * 512 + tid;
    int r = ci >> 2;
    int logc = (ci & 3) ^ ((r >> 1) & 3);
    srcA[i] = A8 + (size_t)(m0 + r) * K + logc * 16;
    srcB[i] = B8 + (size_t)(n0 + r) * K + logc * 16;
  }

  v4f acc[8][4];
  #pragma unroll
  for (int i = 0; i < 8; ++i)
    #pragma unroll
    for (int j = 0; j < 4; ++j) acc[i][j] = (v4f){0.f, 0.f, 0.f, 0.f};

  const int csw = (lc >> 1) & 3;
  int aoff[8], boff[4];
  #pragma unroll
  for (int mi = 0; mi < 8; ++mi) aoff[mi] = (wm * 128 + mi * 16 + lc) * 64 + ((lq ^ csw) << 4);
  #pragma unroll
  for (int ni = 0; ni < 4; ++ni) boff[ni] = (wn * 64 + ni * 16 + lc) * 64 + ((lq ^ csw) << 4);

  auto stageA = [&](int t, int i) {
    gload16(&lds8[(t & 1) * 32768 + i * 8192 + wid * 1024], srcA[i] + t * 64);
  };
  auto stageB = [&](int t, int i) {
    gload16(&lds8[(t & 1) * 32768 + 16384 + i * 8192 + wid * 1024], srcB[i] + t * 64);
  };

  stageA(0, 0); stageA(0, 1); stageB(0, 0); stageB(0, 1);
  stageA(1, 0); stageA(1, 1); stageB(1, 0); stageB(1, 1);
  asm volatile("s_waitcnt vmcnt(4)" ::: "memory");
  __builtin_amdgcn_s_barrier();

  union Frag { v4i v; long long ll[2]; };
  const int NT = K >> 6;
  for (int t = 0; t < NT; ++t) {
    const u8* Ab = &lds8[(t & 1) * 32768];
    const u8* Bb = Ab + 16384;
    Frag fa[8], fb[4];

    // q0: read all B + A0-3 (b128 each, both K-halves); MFMA kh0 mi0-3
    #pragma unroll
    for (int ni = 0; ni < 4; ++ni) fb[ni].v = *(const v4i*)(Bb + boff[ni]);
    #pragma unroll
    for (int mi = 0; mi < 4; ++mi) fa[mi].v = *(const v4i*)(Ab + aoff[mi]);
    asm volatile("s_waitcnt lgkmcnt(0)" ::: "memory");
    __builtin_amdgcn_sched_barrier(0);
    __builtin_amdgcn_s_setprio(1);
    #pragma unroll
    for (int mi = 0; mi < 4; ++mi)
      #pragma unroll
      for (int ni = 0; ni < 4; ++ni)
        acc[mi][ni] = __builtin_amdgcn_mfma_f32_16x16x32_fp8_fp8(fa[mi].ll[0], fb[ni].ll[0], acc[mi][ni], 0, 0, 0);
    __builtin_amdgcn_s_setprio(0);
    __builtin_amdgcn_s_barrier();

    // q1: read A4-7; stage B(t+2).0 into cur B-region (dead after q0 barrier)
    #pragma unroll
    for (int mi = 0; mi < 4; ++mi) fa[mi + 4].v = *(const v4i*)(Ab + aoff[mi + 4]);
    if (t + 2 < NT) stageB(t + 2, 0);
    asm volatile("s_waitcnt lgkmcnt(0)" ::: "memory");
    __builtin_amdgcn_sched_barrier(0);
    __builtin_amdgcn_s_setprio(1);
    #pragma unroll
    for (int mi = 0; mi < 4; ++mi)
      #pragma unroll
      for (int ni = 0; ni < 4; ++ni)
        acc[mi + 4][ni] = __builtin_amdgcn_mfma_f32_16x16x32_fp8_fp8(fa[mi + 4].ll[0], fb[ni].ll[0], acc[mi + 4][ni], 0, 0, 0);
    __builtin_amdgcn_s_setprio(0);
    __builtin_amdgcn_s_barrier();

    // q2: no reads (kh1 from regs); stage B(t+2).1, A(t+2).0 (A dead after q1 barrier)
    if (t + 2 < NT) { stageB(t + 2, 1); stageA(t + 2, 0); }
    __builtin_amdgcn_s_setprio(1);
    #pragma unroll
    for (int mi = 0; mi < 4; ++mi)
      #pragma unroll
      for (int ni = 0; ni < 4; ++ni)
        acc[mi][ni] = __builtin_amdgcn_mfma_f32_16x16x32_fp8_fp8(fa[mi].ll[1], fb[ni].ll[1], acc[mi][ni], 0, 0, 0);
    __builtin_amdgcn_s_setprio(0);
    __builtin_amdgcn_s_barrier();

    // q3: stage A(t+2).1; MFMA kh1 mi4-7; per-tile counted vmcnt
    if (t + 2 < NT) stageA(t + 2, 1);
    __builtin_amdgcn_s_setprio(1);
    #pragma unroll
    for (int mi = 0; mi < 4; ++mi)
      #pragma unroll
      for (int ni = 0; ni < 4; ++ni)
        acc[mi + 4][ni] = __builtin_amdgcn_mfma_f32_16x16x32_fp8_fp8(fa[mi + 4].ll[1], fb[ni].ll[1], acc[mi + 4][ni], 0, 0, 0);
    __builtin_amdgcn_s_setprio(0);
    if (t + 2 < NT) { asm volatile("s_waitcnt vmcnt(4)" ::: "memory"); }
    else            { asm volatile("s_waitcnt vmcnt(0)" ::: "memory"); }
    __builtin_amdgcn_s_barrier();
  }
  asm volatile("s_waitcnt vmcnt(0)" ::: "memory");

  // undo the x64 weight scale
  #pragma unroll
  for (int mi = 0; mi < 8; ++mi)
    #pragma unroll
    for (int ni = 0; ni < 4; ++ni)
      acc[mi][ni] *= 0.015625f;

  if constexpr (EPI == EPI_GLU) {
    #pragma unroll
    for (int mi = 0; mi < 8; ++mi)
      #pragma unroll
      for (int np = 0; np < 2; ++np)
        #pragma unroll
        for (int r = 0; r < 4; ++r) {
          int grow = m0 + wm * 128 + mi * 16 + lq * 4 + r;
          int gcol = (n0 >> 1) + wn * 32 + np * 16 + lc;
          float g = acc[mi][2 * np][r];
          float u = acc[mi][2 * np + 1][r];
          C8[perm8((size_t)grow * ldc + gcol)] = f2fp8(u * g / (1.0f + __expf(-g)));
        }
    return;
  } else {
    // EPI_STATS: epilogue scratch aliased onto (dead) staging LDS
    float* s_mx = (float*)lds8;
    float* s_sm = (float*)(lds8 + 4096);
    int*   s_ax = (int*)(lds8 + 8192);
    __syncthreads();
    #pragma unroll
    for (int mi = 0; mi < 8; ++mi) {
      #pragma unroll
      for (int r = 0; r < 4; ++r) {
        float v0 = acc[mi][0][r], v1 = acc[mi][1][r], v2 = acc[mi][2][r], v3 = acc[mi][3][r];
        float mx = v0; int ax = lc;
        if (v1 > mx) { mx = v1; ax = 16 + lc; }
        if (v2 > mx) { mx = v2; ax = 32 + lc; }
        if (v3 > mx) { mx = v3; ax = 48 + lc; }
        #pragma unroll
        for (int off = 1; off < 16; off <<= 1) {
          float om = __shfl_xor(mx, off); int oa = __shfl_xor(ax, off);
          if (om > mx || (om == mx && oa < ax)) { mx = om; ax = oa; }
        }
        float se = __expf(v0 - mx) + __expf(v1 - mx) + __expf(v2 - mx) + __expf(v3 - mx);
        #pragma unroll
        for (int off = 1; off < 16; off <<= 1) se += __shfl_xor(se, off);
        if (lc == 0) {
          int row = wm * 128 + mi * 16 + lq * 4 + r;
          s_mx[row * 4 + wn] = mx; s_sm[row * 4 + wn] = se; s_ax[row * 4 + wn] = wn * 64 + ax;
        }
      }
    }
    __syncthreads();
    if (tid < 256) {
      float gm = s_mx[tid * 4]; int ga = s_ax[tid * 4];
      #pragma unroll
      for (int w = 1; w < 4; ++w) {
        float m = s_mx[tid * 4 + w];
        if (m > gm) { gm = m; ga = s_ax[tid * 4 + w]; }
      }
      float gs = 0.f;
      #pragma unroll
      for (int w = 0; w < 4; ++w) gs += s_sm[tid * 4 + w] * __expf(s_mx[tid * 4 + w] - gm);
      v4f rec; rec[0] = gm; rec[1] = gs; rec[2] = __int_as_float(n0 + ga); rec[3] = 0.f;
      partials[(size_t)(m0 + tid) * nch + blockIdx.y] = rec;
    }
  }
}

// ---------------------------------------------------------------------------
// PIPELINED 128x128 GEMM fp8 e4m3: BK=64B, 4 waves, 32KB dbuf LDS (4 blk/CU),
// counted vmcnt(4). acc scaled by 1/64 (B weights pre-x64).
template <int EPI>
__launch_bounds__(256, 4)
__global__ void k_gemm9(const u8* __restrict__ A8, const u8* __restrict__ B8,
                        u16* __restrict__ Cbf, float* __restrict__ Cf32,
                        const int* __restrict__ keepArr, RmsSrc rs,
                        int K, int ldb, int ldc) {
  __shared__ __align__(16) u8 lds8[32768];      // buf b at b*16384; A 8KB, B at +8192
  const int tid = threadIdx.x;
  const int lane = tid & 63, wid = tid >> 6;
  const int wm = wid >> 1, wn = wid & 1;        // per-wave out 64x64
  const int lc = lane & 15, lq = lane >> 4;
  const int m0 = blockIdx.x * 128, n0 = blockIdx.y * 128;

  const u8* srcA[2]; const u8* srcB[2];
  #pragma unroll
  for (int i = 0; i < 2; ++i) {
    int ci = i * 256 + tid;
    int r = ci >> 2;
    int logc = (ci & 3) ^ ((r >> 1) & 3);
    srcA[i] = A8 + (size_t)(m0 + r) * K + logc * 16;
    srcB[i] = B8 + (size_t)(n0 + r) * ldb + logc * 16;
  }

  v4f acc[4][4];
  #pragma unroll
  for (int i = 0; i < 4; ++i)
    #pragma unroll
    for (int j = 0; j < 4; ++j) acc[i][j] = (v4f){0.f, 0.f, 0.f, 0.f};

  const int csw = (lc >> 1) & 3;
  int aoff[4], boff[4];
  #pragma unroll
  for (int mi = 0; mi < 4; ++mi) aoff[mi] = (wm * 64 + mi * 16 + lc) * 64 + ((lq ^ csw) << 4);
  #pragma unroll
  for (int ni = 0; ni < 4; ++ni) boff[ni] = (wn * 64 + ni * 16 + lc) * 64 + ((lq ^ csw) << 4);

  auto stageTo = [&](int b, int t) {
    #pragma unroll
    for (int i = 0; i < 2; ++i) {
      gload16(&lds8[b * 16384 + i * 4096 + wid * 1024], srcA[i] + t * 64);
      gload16(&lds8[b * 16384 + 8192 + i * 4096 + wid * 1024], srcB[i] + t * 64);
    }
  };

  stageTo(0, 0);
  union Frag { v4i v; long long ll[2]; };
  const int NT = K >> 6;
  for (int t = 0; t < NT; ++t) {
    const int cur = t & 1;
    if (t + 1 < NT) {
      stageTo(cur ^ 1, t + 1);
      asm volatile("s_waitcnt vmcnt(4)" ::: "memory");
    } else {
      asm volatile("s_waitcnt vmcnt(0)" ::: "memory");
    }
    __builtin_amdgcn_s_barrier();
    const u8* Ab = &lds8[cur * 16384];
    const u8* Bb = Ab + 8192;
    Frag fa[4], fb[4];
    #pragma unroll
    for (int mi = 0; mi < 4; ++mi) fa[mi].v = *(const v4i*)(Ab + aoff[mi]);
    #pragma unroll
    for (int ni = 0; ni < 4; ++ni) fb[ni].v = *(const v4i*)(Bb + boff[ni]);
    __builtin_amdgcn_s_setprio(1);
    #pragma unroll
    for (int mi = 0; mi < 4; ++mi)
      #pragma unroll
      for (int ni = 0; ni < 4; ++ni)
        acc[mi][ni] = __builtin_amdgcn_mfma_f32_16x16x32_fp8_fp8(fa[mi].ll[0], fb[ni].ll[0], acc[mi][ni], 0, 0, 0);
    __builtin_amdgcn_s_setprio(0);
    asm volatile("s_waitcnt lgkmcnt(0)" ::: "memory");
    __builtin_amdgcn_sched_barrier(0);
    __builtin_amdgcn_s_barrier();
    __builtin_amdgcn_s_setprio(1);
    #pragma unroll
    for (int mi = 0; mi < 4; ++mi)
      #pragma unroll
      for (int ni = 0; ni < 4; ++ni)
        acc[mi][ni] = __builtin_amdgcn_mfma_f32_16x16x32_fp8_fp8(fa[mi].ll[1], fb[ni].ll[1], acc[mi][ni], 0, 0, 0);
    __builtin_amdgcn_s_setprio(0);
  }

  #pragma unroll
  for (int mi = 0; mi < 4; ++mi)
    #pragma unroll
    for (int ni = 0; ni < 4; ++ni)
      #pragma unroll
      for (int r = 0; r < 4; ++r) {
        int grow = m0 + wm * 64 + mi * 16 + lq * 4 + r;
        int gcol = n0 + wn * 64 + ni * 16 + lc;
        size_t idx = (size_t)grow * ldc + gcol;
        float vv = acc[mi][ni][r] * 0.015625f;
        if constexpr (EPI == EPI_BF16) {
          Cbf[idx] = f2bf(vv);
        } else if constexpr (EPI == EPI_OEMB) {
          int t_ = grow & 15, bn = grow >> 4;
          int tok = (t_ == 0) ? rs.ftok[bn] : cMASK;
          float kf = (float)keepArr[bn];
          Cf32[idx] = rs.emb[(size_t)tok * cD + gcol] + vv * kf;
        } else {  // EPI_DOWNACC
          Cf32[idx] += vv;
        }
      }
}

// ---------------------------------------------------------------------------
__global__ void k_rope(u16* __restrict__ qb, u16* __restrict__ kb,
                       const int* __restrict__ anchors, const int* __restrict__ cpos) {
  int r = blockIdx.x;
  int which = (r >= MKV);
  int rr = which ? r - MKV : r;
  int j = rr % 17, bn = rr / 17;
  if (!which && j == 0) return;
  u16* buf = which ? kb : qb;
  int pos = (which && j == 0) ? cpos[bn] : (anchors[bn] + j - 1);
  float fp = (float)pos;
  for (int p = threadIdx.x; p < cH * 64; p += 256) {
    int h = p >> 6, i = p & 63;
    size_t base = (size_t)rr * cD + h * cHD;
    float x1 = bf2f(buf[base + i]);
    float x2 = bf2f(buf[base + 64 + i]);
    float freq = powf(10000.0f, -((float)(2 * i)) / 128.0f);
    float ang = fp * freq;
    float sn = sinf(ang), cn = cosf(ang);
    buf[base + i]      = f2bf(x1 * cn - x2 * sn);
    buf[base + 64 + i] = f2bf(x2 * cn + x1 * sn);
  }
}

// Attention. Writes attn-out compact fp8 perm8 (token rows).
__global__ void k_attn(u16* __restrict__ qb, const u16* __restrict__ kb,
                       const u16* __restrict__ vb, u8* __restrict__ ao8) {
  int blk = blockIdx.x;
  int h = blk % cH, bn = blk / cH;
  __shared__ float qs[16][128], ks[17][128], vs[17][128], ps[16][18];
  int lane = threadIdx.x;
  for (int e = lane; e < 16 * 128; e += 64) {
    int r = e >> 7, d = e & 127;
    qs[r][d] = bf2f(qb[((size_t)(bn * 17 + 1 + r)) * cD + h * cHD + d]);
  }
  for (int e = lane; e < 17 * 128; e += 64) {
    int r = e >> 7, d = e & 127;
    ks[r][d] = bf2f(kb[((size_t)(bn * 17 + r)) * cD + h * cHD + d]);
    vs[r][d] = bf2f(vb[((size_t)(bn * 17 + r)) * cD + h * cHD + d]);
  }
  __syncthreads();
  for (int e = lane; e < 16 * 17; e += 64) {
    int qi = e / 17, ki = e % 17;
    float s = 0.f;
    for (int d = 0; d < 128; ++d) s += qs[qi][d] * ks[ki][d];
    ps[qi][ki] = s * 0.08838834764831845f;
  }
  __syncthreads();
  if (lane < 16) {
    float m = -3e38f;
    for (int kk = 0; kk < 17; ++kk) m = fmaxf(m, ps[lane][kk]);
    float s = 0.f;
    for (int kk = 0; kk < 17; ++kk) { float e_ = __expf(ps[lane][kk] - m); ps[lane][kk] = e_; s += e_; }
    float is = 1.0f / s;
    for (int kk = 0; kk < 17; ++kk) ps[lane][kk] *= is;
  }
  __syncthreads();
  for (int e = lane; e < 16 * 128; e += 64) {
    int qi = e >> 7, d = e & 127;
    float s = 0.f;
    for (int kk = 0; kk < 17; ++kk) s += ps[qi][kk] * vs[kk][d];
    ao8[perm8((size_t)(bn * 16 + qi) * cD + h * cHD + d)] = f2fp8(s);
  }
}

__global__ void k_tgt(const u16* __restrict__ hout, const float* __restrict__ Wlm,
                      const int* __restrict__ ids, const int* __restrict__ anchors,
                      int* __restrict__ tgt_tok, float* __restrict__ tgt_logit) {
  int w = threadIdx.x >> 6, lane = threadIdx.x & 63;
  int m = blockIdx.x * 4 + w;
  int bn = m >> 4, t = m & 15, b = bn / cNA;
  int label = anchors[bn] + t;
  int sl = (label < cS - 1) ? label : (cS - 1);
  int tok = ids[(size_t)b * cS + sl];
  const u16* hr = hout + (size_t)m * cD;
  const float* wr = Wlm + (size_t)tok * cD;
  float s = 0.f;
  for (int d = lane; d < cD; d += 64) s += bf2f(hr[d]) * wr[d];
  s = waveSum(s);
  if (lane == 0) { tgt_tok[m] = tok; tgt_logit[m] = s; }
}

__global__ void k_combine(const v4f* __restrict__ partials, const int* __restrict__ tgt_tok,
                          const float* __restrict__ tgt_logit, const int* __restrict__ keepArr,
                          const int* __restrict__ anchors, const float* __restrict__ lmask,
                          float* __restrict__ tokOut, int nch) {
  int m = blockIdx.x;
  int tid = threadIdx.x, lane = tid & 63, w = tid >> 6;
  float cm = -3.0e38f, cs = 0.f; int ca = 0x7fffffff;
  if (tid < nch) {
    v4f rec = partials[(size_t)m * nch + tid];
    cm = rec[0]; cs = rec[1]; ca = __float_as_int(rec[2]);
  }
  float gm = cm; int ga = ca;
  #pragma unroll
  for (int off = 1; off < 64; off <<= 1) {
    float om = __shfl_xor(gm, off); int oa = __shfl_xor(ga, off);
    if (om > gm || (om == gm && oa < ga)) { gm = om; ga = oa; }
  }
  __shared__ float wmx[4]; __shared__ int wax[4]; __shared__ float wsm[4];
  if (lane == 0) { wmx[w] = gm; wax[w] = ga; }
  __syncthreads();
  if (tid == 0) {
    for (int i = 1; i < 4; ++i)
      if (wmx[i] > wmx[0] || (wmx[i] == wmx[0] && wax[i] < wax[0])) { wmx[0] = wmx[i]; wax[0] = wax[i]; }
  }
  __syncthreads();
  gm = wmx[0]; ga = wax[0];
  float s = (tid < nch) ? cs * __expf(cm - gm) : 0.f;
  s = waveSum(s);
  if (lane == 0) wsm[w] = s;
  __syncthreads();
  if (tid == 0) {
    float gs = wsm[0] + wsm[1] + wsm[2] + wsm[3];
    float logZ = gm + logf(gs);
    int bn = m >> 4, t = m & 15, b = bn / cNA;
    int label = anchors[bn] + t;
    int sl = (label < cS - 1) ? label : (cS - 1);
    float wgt = (float)keepArr[bn] * ((t > 0) ? 1.f : 0.f) * ((label < cS) ? 1.f : 0.f) *
                lmask[(size_t)b * cS + sl];
    float lp = tgt_logit[m] - logZ;
    int tg = tgt_tok[m];
    tokOut[m * 4 + 0] = lp * wgt;
    tokOut[m * 4 + 1] = wgt;
    tokOut[m * 4 + 2] = ((ga == tg) && (wgt > 0.5f)) ? 1.f : 0.f;
    tokOut[m * 4 + 3] = 0.f;
  }
}

__global__ void k_final(const float* __restrict__ tokOut, float* __restrict__ outp) {
  int tid = threadIdx.x;
  float swl = 0.f, sw = 0.f, sm = 0.f;
  for (int m = tid; m < MTOK; m += 256) {
    swl += tokOut[m * 4 + 0];
    sw  += tokOut[m * 4 + 1];
    sm  += tokOut[m * 4 + 2];
  }
  swl = waveSum(swl); sw = waveSum(sw); sm = waveSum(sm);
  __shared__ float r0[4], r1[4], r2[4];
  int lane = tid & 63, w = tid >> 6;
  if (lane == 0) { r0[w] = swl; r1[w] = sw; r2[w] = sm; }
  __syncthreads();
  if (tid == 0) {
    float a = r0[0] + r0[1] + r0[2] + r0[3];
    float b = r1[0] + r1[1] + r1[2] + r1[3];
    float c = r2[0] + r2[1] + r2[2] + r2[3];
    float denom = b + 1e-6f;
    float loss = -a / denom;
    float acc  = c / denom;
    if (b == 0.0f) loss = -300.0f;
    outp[0] = loss;
    outp[1] = acc;
  }
}

__global__ void k_sentinel(float* outp) {
  if (threadIdx.x == 0) { outp[0] = -777.0f; outp[1] = -777.0f; }
}

// ---------------------------------------------------------------------------
extern "C" void kernel_launch(void* const* d_in, const int* in_sizes, int n_in,
                              void* d_out, int out_size, void* d_ws, size_t ws_size,
                              hipStream_t stream) {
  const int*   ids   = (const int*)  d_in[0];
  const float* hs    = (const float*)d_in[1];
  const float* lmask = (const float*)d_in[2];
  const float* rv    = (const float*)d_in[3];
  const float* emb   = (const float*)d_in[4];
  const float* wlm   = (const float*)d_in[5];
  const float* wq    = (const float*)d_in[6];
  const float* wk    = (const float*)d_in[7];
  const float* wv    = (const float*)d_in[8];
  const float* wo    = (const float*)d_in[9];
  const float* wg    = (const float*)d_in[10];
  const float* wu    = (const float*)d_in[11];
  const float* wd    = (const float*)d_in[12];
  const float* nattn = (const float*)d_in[13];
  const float* nmlp  = (const float*)d_in[14];
  const float* nout  = (const float*)d_in[15];
  const float* nchs  = (const float*)d_in[16];
  (void)in_sizes; (void)n_in; (void)out_size;

  float* outp = (float*)d_out;

  char* wsb = (char*)d_ws;
  size_t off = 0;
  auto alloc = [&](size_t bytes) -> void* {
    void* p = wsb + off;
    off = (off + bytes + 255) & ~(size_t)255;
    return p;
  };
  int*   anchors = (int*)  alloc((size_t)cB * cNA * 4);
  int*   keepA   = (int*)  alloc((size_t)cB * cNA * 4);
  int*   ftok    = (int*)  alloc((size_t)cB * cNA * 4);
  int*   cpos    = (int*)  alloc((size_t)cB * cNA * 4);
  int*   self    = (int*)  alloc((size_t)cB * NCAND * 4);
  float* rowinv  = (float*)alloc((size_t)MKV * 4);
  int*   ttok    = (int*)  alloc((size_t)MTOK * 4);
  float* tlogit  = (float*)alloc((size_t)MTOK * 4);
  float* tokOut  = (float*)alloc((size_t)MTOK * 4 * 4);

  const size_t szQ  = (size_t)MKV * cD * 2;           // 17.8 MB (q -> h -> h_out)
  const size_t szX  = (size_t)MTOK * cD * 4;          // 33.6 MB (fp32 residual)
  u16* qb = (u16*)alloc(szQ);
  const size_t a1off = off;

  RmsSrc rs{hs, emb, nattn, nchs, rowinv, ftok, cpos};

  // common head
  k_select <<<dim3(cB * 16), 256, 0, stream>>>(lmask, rv, self);
  k_anchors<<<dim3(cB),      256, 0, stream>>>(lmask, self, ids, anchors, keepA, ftok, cpos);

  // ---------------- fast tier
  size_t kvb_off  = a1off;                            // kv8 fp8: 8.9 MB
  size_t a1f_off  = (kvb_off + szQ + 255) & ~(size_t)255;
  size_t a1f_sz   = 2 * szQ > (szX + (size_t)MTOK * 4096 * 2) ? 2 * szQ
                                                             : (szX + (size_t)MTOK * 4096 * 2);
  size_t wreg_off = (a1f_off + a1f_sz + 255) & ~(size_t)255;
  size_t wreg_sz  = (size_t)cV * cD * 2;              // 131 MB (largest stage)
  size_t need_fast = wreg_off + wreg_sz;

  if (need_fast <= ws_size) {
    u8*    kv8   = (u8*)(wsb + kvb_off);
    u16*   kb    = (u16*)(wsb + a1f_off);
    u16*   vb    = (u16*)(wsb + a1f_off + szQ);
    float* xb    = (float*)(wsb + a1f_off);
    u8*    ao8   = (u8*)(wsb + a1f_off + 2 * szQ);
    u8*    cbuf8 = (u8*)(wsb + a1f_off + 2 * szQ + (size_t)MTOK * cD);
    v4f*   parts = (v4f*)(wsb + a1f_off);             // lm-head stage (xb dead)
    u8*    h8    = (u8*)(wsb + a1f_off + (size_t)16 * 1024 * 1024);
    u16*   hb    = qb;
    u16*   houtb = qb;
    u16*   wT    = (u16*)(wsb + wreg_off);
    const size_t szDD = (size_t)cD * cD;
    u8* wq8 = (u8*)wT;        u8* wk8 = wq8 + szDD;
    u8* wv8 = wq8 + 2 * szDD; u8* wo8 = wq8 + 3 * szDD;
    const size_t szDF = (size_t)cD * cDFF;
    u8* wgu8 = (u8*)wT;                               // stage 2: 33.5 MB
    u8* wd8  = (u8*)wT + 2 * szDF;
    u8* h8m  = (u8*)wT + 3 * szDF;
    u8* wlm8 = (u8*)wT;                               // stage 3: 65.5 MB

    k_build2<<<dim3(MKV), 256, 0, stream>>>(hs, emb, nattn, nchs, ftok, cpos, kv8);

    k_tconv8<<<dim3(32, 32), 256, 0, stream>>>(wq, wq8, cD, cD, -1, 64.0f);
    k_tconv8<<<dim3(32, 32), 256, 0, stream>>>(wk, wk8, cD, cD, -1, 64.0f);
    k_tconv8<<<dim3(32, 32), 256, 0, stream>>>(wv, wv8, cD, cD, -1, 64.0f);
    k_tconv8<<<dim3(32, 32), 256, 0, stream>>>(wo, wo8, cD, cD, -1, 64.0f);

    k_gemm9<EPI_BF16><<<dim3(MKV / 128, cD / 128), 256, 0, stream>>>(
        kv8, wq8, qb, nullptr, nullptr, rs, cD, cD, cD);
    k_gemm9<EPI_BF16><<<dim3(MKV / 128, cD / 128), 256, 0, stream>>>(
        kv8, wk8, kb, nullptr, nullptr, rs, cD, cD, cD);
    k_gemm9<EPI_BF16><<<dim3(MKV / 128, cD / 128), 256, 0, stream>>>(
        kv8, wv8, vb, nullptr, nullptr, rs, cD, cD, cD);

    k_rope<<<dim3(2 * MKV), 256, 0, stream>>>(qb, kb, anchors, cpos);
    k_attn<<<dim3(cB * cNA * cH), 64, 0, stream>>>(qb, kb, vb, ao8);

    k_gemm9<EPI_OEMB><<<dim3(MTOK / 128, cD / 128), 256, 0, stream>>>(
        ao8, wo8, nullptr, xb, keepA, rs, cD, cD, cD);

    k_rms<<<dim3(MTOK), 256, 0, stream>>>(xb, nmlp, hb);
    k_cvt8<<<dim3(1024), 256, 0, stream>>>(hb, h8m, (long)MTOK * cD);

    k_tconv8<<<dim3(128, 32), 256, 0, stream>>>(wg, wgu8, cD, cDFF, 0, 64.0f);
    k_tconv8<<<dim3(128, 32), 256, 0, stream>>>(wu, wgu8, cD, cDFF, 16, 64.0f);
    k_tconv8<<<dim3(32, 128), 256, 0, stream>>>(wd, wd8, cDFF, cD, -1, 64.0f);

    for (int cb = 0; cb < cDFF; cb += 4096) {
      k_gemm8<EPI_GLU><<<dim3(MTOK / 256, 32), 512, 0, stream>>>(
          h8m, wgu8 + (size_t)cb * 2 * cD, cbuf8, nullptr, cD, 4096, 0);
      k_gemm9<EPI_DOWNACC><<<dim3(MTOK / 128, cD / 128), 256, 0, stream>>>(
          cbuf8, wd8 + cb, nullptr, xb, nullptr, rs, 4096, cDFF, cD);
    }

    k_rms<<<dim3(MTOK), 256, 0, stream>>>(xb, nout, houtb);

    k_tgt<<<dim3(MTOK / 4), 256, 0, stream>>>(houtb, wlm, ids, anchors, ttok, tlogit);

    k_cvt8 <<<dim3(1024), 256, 0, stream>>>(houtb, h8, (long)MTOK * cD);
    k_conv8<<<dim3(2048), 256, 0, stream>>>(wlm, wlm8, (long)cV * cD, 64.0f);
    k_gemm8<EPI_STATS><<<dim3(MTOK / 256, NCH2), 512, 0, stream>>>(
        h8, wlm8, nullptr, parts, cD, 0, NCH2);

    k_combine<<<dim3(MTOK), 256, 0, stream>>>(parts, ttok, tlogit, keepA, anchors, lmask, tokOut, NCH2);
    k_final  <<<dim3(1), 256, 0, stream>>>(tokOut, outp);
    return;
  }

  // ---------------- fallback: signal insufficient workspace
  k_sentinel<<<dim3(1), 64, 0, stream>>>(outp);
}

// Round 18
// 1433.516 us; speedup vs baseline: 1.6959x; 1.0008x over previous
//
#include <hip/hip_runtime.h>
#include <math.h>

typedef unsigned short u16;
typedef unsigned char u8;
typedef short v8s __attribute__((ext_vector_type(8)));
typedef u16   v4u __attribute__((ext_vector_type(4)));
typedef float v4f __attribute__((ext_vector_type(4)));
typedef int   v2i __attribute__((ext_vector_type(2)));
typedef int   v4i __attribute__((ext_vector_type(4)));

#define DEVFN static __device__ __forceinline__

constexpr int cB = 2, cS = 4096, cD = 2048, cV = 32000, cH = 16, cHD = 128;
constexpr int cBS = 16, cNA = 128, cMASK = 31999, cDFF = 8192;
constexpr int NCAND = cS - cBS + 1;   // 4081 anchor candidates
constexpr int MTOK  = cB * cNA * cBS; // 4096 query tokens
constexpr int MKV   = cB * cNA * 17;  // 4352 kv rows (ctx + 16)
constexpr int NCH2  = cV / 256;       // 125 vocab chunks (256-wide)

constexpr int EPI_BF16 = 0, EPI_OEMB = 2, EPI_DOWNACC = 3, EPI_STATS = 4, EPI_GLU = 5;

struct RmsSrc {
  const float* hs; const float* emb; const float* nattn; const float* nchs;
  const float* rowinv; const int* ftok; const int* cpos;
};

DEVFN u16 f2bf(float f) {               // RNE fp32 -> bf16
  union { float f; unsigned u; } a; a.f = f;
  unsigned u = a.u;
  u = u + 0x7fffu + ((u >> 16) & 1u);
  return (u16)(u >> 16);
}
DEVFN float bf2f(u16 h) {
  union { unsigned u; float f; } a; a.u = ((unsigned)h) << 16;
  return a.f;
}
DEVFN float waveSum(float v) {
  #pragma unroll
  for (int o = 32; o >= 1; o >>= 1) v += __shfl_xor(v, o);
  return v;
}
DEVFN void gload16(void* lds, const void* g) {
  __builtin_amdgcn_global_load_lds(
      (const __attribute__((address_space(1))) unsigned*)g,
      (__attribute__((address_space(3))) unsigned*)lds, 16, 0, 0);
}
DEVFN int pack4fp8(float a, float b, float c, float d) {
  int p = __builtin_amdgcn_cvt_pk_fp8_f32(a, b, 0, 0);
  p = __builtin_amdgcn_cvt_pk_fp8_f32(c, d, p, 1);
  return p;
}
DEVFN u8 f2fp8(float v) {
  return (u8)(__builtin_amdgcn_cvt_pk_fp8_f32(v, 0.f, 0, 0) & 0xff);
}
// permuted output offset for fp8 buffers: within each 64B K-group,
// newpos = lq*16 + kh*8 + j  for k = kh*32 + lq*8 + j
DEVFN long perm8(long i) {
  return (i & ~63L) | (((i >> 3) & 3) << 4) | (((i >> 5) & 1) << 3);
}
// bijective XCD-chunk remap: hardware assigns XCD = orig%8 (round-robin);
// remap so each XCD owns a contiguous chunk of logical block ids (L2 reuse).
DEVFN int xcd_swz(int lin, int nwg) {
  int q = nwg >> 3, r = nwg & 7;
  int xcd = lin & 7, idx = lin >> 3;
  return (xcd < r ? xcd * (q + 1) : r * (q + 1) + (xcd - r) * q) + idx;
}

// ---------------------------------------------------------------------------
__global__ void k_select(const float* __restrict__ lmask, const float* __restrict__ rv_in,
                         int* __restrict__ self) {
  int b = blockIdx.x >> 4, chunk = blockIdx.x & 15;
  __shared__ float rvs[4096];
  for (int i = threadIdx.x; i < NCAND; i += 256) {
    bool valid = lmask[(size_t)b * cS + i] > 0.5f;
    rvs[i] = valid ? rv_in[(size_t)b * NCAND + i] : 2.0f;
  }
  __syncthreads();
  int i = chunk * 256 + threadIdx.x;
  if (i < NCAND) {
    float v = rvs[i];
    int rank = 0;
    for (int j = 0; j < NCAND; ++j) {
      float u = rvs[j];
      rank += (u < v) || (u == v && j < i);
    }
    self[(size_t)b * NCAND + i] = (rank < cNA) ? 1 : 0;
  }
}

__global__ void k_anchors(const float* __restrict__ lmask, const int* __restrict__ self,
                          const int* __restrict__ ids, int* __restrict__ anchors,
                          int* __restrict__ keepA, int* __restrict__ ftok, int* __restrict__ cpos) {
  int b = blockIdx.x;
  __shared__ int flags[4096];
  __shared__ int ssum[256];
  __shared__ int soff[257];
  __shared__ int abuf[cNA];
  for (int i = threadIdx.x; i < 4096; i += 256)
    flags[i] = (i < NCAND) ? (self[(size_t)b * NCAND + i] && (lmask[(size_t)b * cS + i] > 0.5f)) : 0;
  if (threadIdx.x < cNA) abuf[threadIdx.x] = 0;
  __syncthreads();
  int s = 0;
  #pragma unroll
  for (int j = 0; j < 16; ++j) s += flags[threadIdx.x * 16 + j];
  ssum[threadIdx.x] = s;
  __syncthreads();
  if (threadIdx.x == 0) {
    int a = 0;
    for (int t = 0; t < 256; ++t) { soff[t] = a; a += ssum[t]; }
    soff[256] = a;
  }
  __syncthreads();
  int nsel = soff[256];
  int p = soff[threadIdx.x];
  for (int j = 0; j < 16; ++j) {
    int i = threadIdx.x * 16 + j;
    if (flags[i]) { if (p < cNA) abuf[p] = i; ++p; }
  }
  __syncthreads();
  if (threadIdx.x < cNA) {
    int q = threadIdx.x;
    int kp = (q < nsel) ? 1 : 0;
    int a = kp ? abuf[q] : 0;
    anchors[b * cNA + q] = a;
    keepA[b * cNA + q] = kp;
    int av = a; if (av < 0) av = 0; if (av > cS - 1) av = cS - 1;
    int tok = ids[(size_t)b * cS + av];
    ftok[b * cNA + q] = kp ? tok : cMASK;
    cpos[b * cNA + q] = (a - 1 > 0) ? (a - 1) : 0;
  }
}

// kv_in = rms'd rows, materialized fp8 perm8. grid: MKV x 256
__global__ void k_build2(const float* __restrict__ hs, const float* __restrict__ emb,
                         const float* __restrict__ nattn, const float* __restrict__ nchs,
                         const int* __restrict__ ftok, const int* __restrict__ cpos,
                         u8* __restrict__ kv8) {
  int r = blockIdx.x;
  int j = r % 17, bn = r / 17, b = bn >> 7;
  const float* src; const float* w;
  if (j == 0) { src = hs + ((size_t)b * cS + cpos[bn]) * cD; w = nchs; }
  else {
    int tok = (j == 1) ? ftok[bn] : cMASK;
    src = emb + (size_t)tok * cD; w = nattn;
  }
  float ss = 0.f;
  for (int d = threadIdx.x; d < cD; d += 256) { float v = src[d]; ss += v * v; }
  ss = waveSum(ss);
  __shared__ float red[4];
  if ((threadIdx.x & 63) == 0) red[threadIdx.x >> 6] = ss;
  __syncthreads();
  float tot = red[0] + red[1] + red[2] + red[3];
  float inv = 1.0f / sqrtf(tot / cD + 1e-6f);
  for (int d = threadIdx.x; d < cD; d += 256)
    kv8[perm8((size_t)r * cD + d)] = f2fp8(src[d] * inv * w[d]);
}

// RMS over fp32 rows -> bf16
__global__ void k_rms(const float* __restrict__ xin, const float* __restrict__ w,
                      u16* __restrict__ outp) {
  int m = blockIdx.x;
  const float* row = xin + (size_t)m * cD;
  float ss = 0.f;
  for (int d = threadIdx.x; d < cD; d += 256) { float v = row[d]; ss += v * v; }
  ss = waveSum(ss);
  __shared__ float red[4];
  if ((threadIdx.x & 63) == 0) red[threadIdx.x >> 6] = ss;
  __syncthreads();
  float tot = red[0] + red[1] + red[2] + red[3];
  float inv = 1.0f / sqrtf(tot / cD + 1e-6f);
  for (int d = threadIdx.x; d < cD; d += 256)
    outp[(size_t)m * cD + d] = f2bf(row[d] * inv * w[d]);
}

// fp32 -> fp8 e4m3 with scale, PERMUTED 64B-group layout. 8 elems/thread
__global__ void k_conv8(const float* __restrict__ in, u8* __restrict__ out, long n, float scale) {
  long i = ((long)blockIdx.x * 256 + threadIdx.x) * 8;
  long stride = (long)gridDim.x * 256 * 8;
  for (; i < n; i += stride) {
    v4f a = *(const v4f*)(in + i), b = *(const v4f*)(in + i + 4);
    v2i pk;
    pk[0] = pack4fp8(a[0] * scale, a[1] * scale, a[2] * scale, a[3] * scale);
    pk[1] = pack4fp8(b[0] * scale, b[1] * scale, b[2] * scale, b[3] * scale);
    *(v2i*)(out + perm8(i)) = pk;
  }
}

// bf16 -> fp8 e4m3, PERMUTED 64B-group layout. 8 elems/thread
__global__ void k_cvt8(const u16* __restrict__ in, u8* __restrict__ out, long n) {
  long i = ((long)blockIdx.x * 256 + threadIdx.x) * 8;
  long stride = (long)gridDim.x * 256 * 8;
  for (; i < n; i += stride) {
    v8s a = *(const v8s*)(in + i);
    v2i pk;
    pk[0] = pack4fp8(bf2f((u16)a[0]), bf2f((u16)a[1]), bf2f((u16)a[2]), bf2f((u16)a[3]));
    pk[1] = pack4fp8(bf2f((u16)a[4]), bf2f((u16)a[5]), bf2f((u16)a[6]), bf2f((u16)a[7]));
    *(v2i*)(out + perm8(i)) = pk;
  }
}

// transpose + fp8(scale) + perm8; goff>=0: gate/up interleave (col j -> row
// (j>>4)*32+goff+(j&15)); goff<0: plain (row = col j)
__global__ void k_tconv8(const float* __restrict__ W, u8* __restrict__ WT8,
                         int K, int N, int goff, float scale) {
  __shared__ float tf[64][65];
  int n0 = blockIdx.x * 64, k0 = blockIdx.y * 64;
  int tid = threadIdx.x;
  int c4 = (tid & 15) * 4, r0 = tid >> 4;
  #pragma unroll
  for (int rr = 0; rr < 64; rr += 16) {
    int k = r0 + rr;
    v4f v = *(const v4f*)(W + (size_t)(k0 + k) * N + n0 + c4);
    #pragma unroll
    for (int e = 0; e < 4; ++e) tf[c4 + e][k] = v[e];
  }
  __syncthreads();
  int n = tid >> 2, kq = (tid & 3) * 16;
  int gn = n0 + n;
  size_t rout = (goff >= 0) ? (((size_t)(gn >> 4) << 5) + goff + (gn & 15)) : (size_t)gn;
  long base = (long)rout * K + k0 + kq;
  v2i p0, p1;
  p0[0] = pack4fp8(tf[n][kq + 0] * scale, tf[n][kq + 1] * scale, tf[n][kq + 2] * scale, tf[n][kq + 3] * scale);
  p0[1] = pack4fp8(tf[n][kq + 4] * scale, tf[n][kq + 5] * scale, tf[n][kq + 6] * scale, tf[n][kq + 7] * scale);
  p1[0] = pack4fp8(tf[n][kq + 8] * scale, tf[n][kq + 9] * scale, tf[n][kq + 10] * scale, tf[n][kq + 11] * scale);
  p1[1] = pack4fp8(tf[n][kq + 12] * scale, tf[n][kq + 13] * scale, tf[n][kq + 14] * scale, tf[n][kq + 15] * scale);
  *(v2i*)(WT8 + perm8(base)) = p0;
  *(v2i*)(WT8 + perm8(base + 8)) = p1;
}

// ---------------------------------------------------------------------------
// 8-PHASE PIPELINED 256x256 GEMM fp8 e4m3 (round-12 verified double-buffer
// form): b128 fragment reads, 64KB LDS (2 blk/CU), t+2 lookahead, vmcnt(4).
// XCD-chunk block swizzle for B-panel L2 reuse.
// EPI_STATS: softmax partials (logits = acc/64). EPI_GLU: interleaved gate/up,
// out fp8 perm8 = up * silu(gate) (weights pre-scaled x64 -> acc/64).
template <int EPI>
__launch_bounds__(512, 2)
__global__ void k_gemm8(const u8* __restrict__ A8, const u8* __restrict__ B8,
                        u8* __restrict__ C8, v4f* __restrict__ partials,
                        int K, int ldc, int nch) {
  __shared__ __align__(16) u8 lds8[65536];
  const int tid = threadIdx.x;
  const int lane = tid & 63, wid = tid >> 6;
  const int wm = wid >> 2, wn = wid & 3;        // per-wave out 128x64
  const int lc = lane & 15, lq = lane >> 4;
  const int gx = gridDim.x;
  int lin = xcd_swz(blockIdx.y * gx + blockIdx.x, gx * gridDim.y);
  const int bix = lin % gx, biy = lin / gx;
  const int m0 = bix * 256, n0 = biy * 256;

  const u8* srcA[2]; const u8* srcB[2];
  #pragma unroll
  for (int i = 0; i < 2; ++i) {
    int ci = i * 512 + tid;
    int r = ci >> 2;
    int logc = (ci & 3) ^ ((r >> 1) & 3);
    srcA[i] = A8 + (size_t)(m0 + r) * K + logc * 16;
    srcB[i] = B8 + (size_t)(n0 + r) * K + logc * 16;
  }

  v4f acc[8][4];
  #pragma unroll
  for (int i = 0; i < 8; ++i)
    #pragma unroll
    for (int j = 0; j < 4; ++j) acc[i][j] = (v4f){0.f, 0.f, 0.f, 0.f};

  const int csw = (lc >> 1) & 3;
  int aoff[8], boff[4];
  #pragma unroll
  for (int mi = 0; mi < 8; ++mi) aoff[mi] = (wm * 128 + mi * 16 + lc) * 64 + ((lq ^ csw) << 4);
  #pragma unroll
  for (int ni = 0; ni < 4; ++ni) boff[ni] = (wn * 64 + ni * 16 + lc) * 64 + ((lq ^ csw) << 4);

  auto stageA = [&](int t, int i) {
    gload16(&lds8[(t & 1) * 32768 + i * 8192 + wid * 1024], srcA[i] + t * 64);
  };
  auto stageB = [&](int t, int i) {
    gload16(&lds8[(t & 1) * 32768 + 16384 + i * 8192 + wid * 1024], srcB[i] + t * 64);
  };

  stageA(0, 0); stageA(0, 1); stageB(0, 0); stageB(0, 1);
  stageA(1, 0); stageA(1, 1); stageB(1, 0); stageB(1, 1);
  asm volatile("s_waitcnt vmcnt(4)" ::: "memory");
  __builtin_amdgcn_s_barrier();

  union Frag { v4i v; long long ll[2]; };
  const int NT = K >> 6;
  for (int t = 0; t < NT; ++t) {
    const u8* Ab = &lds8[(t & 1) * 32768];
    const u8* Bb = Ab + 16384;
    Frag fa[8], fb[4];

    // q0: read all B + A0-3 (b128 each, both K-halves); MFMA kh0 mi0-3
    #pragma unroll
    for (int ni = 0; ni < 4; ++ni) fb[ni].v = *(const v4i*)(Bb + boff[ni]);
    #pragma unroll
    for (int mi = 0; mi < 4; ++mi) fa[mi].v = *(const v4i*)(Ab + aoff[mi]);
    asm volatile("s_waitcnt lgkmcnt(0)" ::: "memory");
    __builtin_amdgcn_sched_barrier(0);
    __builtin_amdgcn_s_setprio(1);
    #pragma unroll
    for (int mi = 0; mi < 4; ++mi)
      #pragma unroll
      for (int ni = 0; ni < 4; ++ni)
        acc[mi][ni] = __builtin_amdgcn_mfma_f32_16x16x32_fp8_fp8(fa[mi].ll[0], fb[ni].ll[0], acc[mi][ni], 0, 0, 0);
    __builtin_amdgcn_s_setprio(0);
    __builtin_amdgcn_s_barrier();

    // q1: read A4-7; stage B(t+2).0 into cur B-region (dead after q0 barrier)
    #pragma unroll
    for (int mi = 0; mi < 4; ++mi) fa[mi + 4].v = *(const v4i*)(Ab + aoff[mi + 4]);
    if (t + 2 < NT) stageB(t + 2, 0);
    asm volatile("s_waitcnt lgkmcnt(0)" ::: "memory");
    __builtin_amdgcn_sched_barrier(0);
    __builtin_amdgcn_s_setprio(1);
    #pragma unroll
    for (int mi = 0; mi < 4; ++mi)
      #pragma unroll
      for (int ni = 0; ni < 4; ++ni)
        acc[mi + 4][ni] = __builtin_amdgcn_mfma_f32_16x16x32_fp8_fp8(fa[mi + 4].ll[0], fb[ni].ll[0], acc[mi + 4][ni], 0, 0, 0);
    __builtin_amdgcn_s_setprio(0);
    __builtin_amdgcn_s_barrier();

    // q2: no reads (kh1 from regs); stage B(t+2).1, A(t+2).0 (A dead after q1 barrier)
    if (t + 2 < NT) { stageB(t + 2, 1); stageA(t + 2, 0); }
    __builtin_amdgcn_s_setprio(1);
    #pragma unroll
    for (int mi = 0; mi < 4; ++mi)
      #pragma unroll
      for (int ni = 0; ni < 4; ++ni)
        acc[mi][ni] = __builtin_amdgcn_mfma_f32_16x16x32_fp8_fp8(fa[mi].ll[1], fb[ni].ll[1], acc[mi][ni], 0, 0, 0);
    __builtin_amdgcn_s_setprio(0);
    __builtin_amdgcn_s_barrier();

    // q3: stage A(t+2).1; MFMA kh1 mi4-7; per-tile counted vmcnt
    if (t + 2 < NT) stageA(t + 2, 1);
    __builtin_amdgcn_s_setprio(1);
    #pragma unroll
    for (int mi = 0; mi < 4; ++mi)
      #pragma unroll
      for (int ni = 0; ni < 4; ++ni)
        acc[mi + 4][ni] = __builtin_amdgcn_mfma_f32_16x16x32_fp8_fp8(fa[mi + 4].ll[1], fb[ni].ll[1], acc[mi + 4][ni], 0, 0, 0);
    __builtin_amdgcn_s_setprio(0);
    if (t + 2 < NT) { asm volatile("s_waitcnt vmcnt(4)" ::: "memory"); }
    else            { asm volatile("s_waitcnt vmcnt(0)" ::: "memory"); }
    __builtin_amdgcn_s_barrier();
  }
  asm volatile("s_waitcnt vmcnt(0)" ::: "memory");

  // undo the x64 weight scale
  #pragma unroll
  for (int mi = 0; mi < 8; ++mi)
    #pragma unroll
    for (int ni = 0; ni < 4; ++ni)
      acc[mi][ni] *= 0.015625f;

  if constexpr (EPI == EPI_GLU) {
    #pragma unroll
    for (int mi = 0; mi < 8; ++mi)
      #pragma unroll
      for (int np = 0; np < 2; ++np)
        #pragma unroll
        for (int r = 0; r < 4; ++r) {
          int grow = m0 + wm * 128 + mi * 16 + lq * 4 + r;
          int gcol = (n0 >> 1) + wn * 32 + np * 16 + lc;
          float g = acc[mi][2 * np][r];
          float u = acc[mi][2 * np + 1][r];
          C8[perm8((size_t)grow * ldc + gcol)] = f2fp8(u * g / (1.0f + __expf(-g)));
        }
    return;
  } else {
    // EPI_STATS: epilogue scratch aliased onto (dead) staging LDS
    float* s_mx = (float*)lds8;
    float* s_sm = (float*)(lds8 + 4096);
    int*   s_ax = (int*)(lds8 + 8192);
    __syncthreads();
    #pragma unroll
    for (int mi = 0; mi < 8; ++mi) {
      #pragma unroll
      for (int r = 0; r < 4; ++r) {
        float v0 = acc[mi][0][r], v1 = acc[mi][1][r], v2 = acc[mi][2][r], v3 = acc[mi][3][r];
        float mx = v0; int ax = lc;
        if (v1 > mx) { mx = v1; ax = 16 + lc; }
        if (v2 > mx) { mx = v2; ax = 32 + lc; }
        if (v3 > mx) { mx = v3; ax = 48 + lc; }
        #pragma unroll
        for (int off = 1; off < 16; off <<= 1) {
          float om = __shfl_xor(mx, off); int oa = __shfl_xor(ax, off);
          if (om > mx || (om == mx && oa < ax)) { mx = om; ax = oa; }
        }
        float se = __expf(v0 - mx) + __expf(v1 - mx) + __expf(v2 - mx) + __expf(v3 - mx);
        #pragma unroll
        for (int off = 1; off < 16; off <<= 1) se += __shfl_xor(se, off);
        if (lc == 0) {
          int row = wm * 128 + mi * 16 + lq * 4 + r;
          s_mx[row * 4 + wn] = mx; s_sm[row * 4 + wn] = se; s_ax[row * 4 + wn] = wn * 64 + ax;
        }
      }
    }
    __syncthreads();
    if (tid < 256) {
      float gm = s_mx[tid * 4]; int ga = s_ax[tid * 4];
      #pragma unroll
      for (int w = 1; w < 4; ++w) {
        float m = s_mx[tid * 4 + w];
        if (m > gm) { gm = m; ga = s_ax[tid * 4 + w]; }
      }
      float gs = 0.f;
      #pragma unroll
      for (int w = 0; w < 4; ++w) gs += s_sm[tid * 4 + w] * __expf(s_mx[tid * 4 + w] - gm);
      v4f rec; rec[0] = gm; rec[1] = gs; rec[2] = __int_as_float(n0 + ga); rec[3] = 0.f;
      partials[(size_t)(m0 + tid) * nch + biy] = rec;
    }
  }
}

// ---------------------------------------------------------------------------
// PIPELINED 128x128 GEMM fp8 e4m3: BK=64B, 4 waves, 32KB dbuf LDS (4 blk/CU),
// counted vmcnt(4). acc scaled by 1/64 (B weights pre-x64).
template <int EPI>
__launch_bounds__(256, 4)
__global__ void k_gemm9(const u8* __restrict__ A8, const u8* __restrict__ B8,
                        u16* __restrict__ Cbf, float* __restrict__ Cf32,
                        const int* __restrict__ keepArr, RmsSrc rs,
                        int K, int ldb, int ldc) {
  __shared__ __align__(16) u8 lds8[32768];      // buf b at b*16384; A 8KB, B at +8192
  const int tid = threadIdx.x;
  const int lane = tid & 63, wid = tid >> 6;
  const int wm = wid >> 1, wn = wid & 1;        // per-wave out 64x64
  const int lc = lane & 15, lq = lane >> 4;
  const int m0 = blockIdx.x * 128, n0 = blockIdx.y * 128;

  const u8* srcA[2]; const u8* srcB[2];
  #pragma unroll
  for (int i = 0; i < 2; ++i) {
    int ci = i * 256 + tid;
    int r = ci >> 2;
    int logc = (ci & 3) ^ ((r >> 1) & 3);
    srcA[i] = A8 + (size_t)(m0 + r) * K + logc * 16;
    srcB[i] = B8 + (size_t)(n0 + r) * ldb + logc * 16;
  }

  v4f acc[4][4];
  #pragma unroll
  for (int i = 0; i < 4; ++i)
    #pragma unroll
    for (int j = 0; j < 4; ++j) acc[i][j] = (v4f){0.f, 0.f, 0.f, 0.f};

  const int csw = (lc >> 1) & 3;
  int aoff[4], boff[4];
  #pragma unroll
  for (int mi = 0; mi < 4; ++mi) aoff[mi] = (wm * 64 + mi * 16 + lc) * 64 + ((lq ^ csw) << 4);
  #pragma unroll
  for (int ni = 0; ni < 4; ++ni) boff[ni] = (wn * 64 + ni * 16 + lc) * 64 + ((lq ^ csw) << 4);

  auto stageTo = [&](int b, int t) {
    #pragma unroll
    for (int i = 0; i < 2; ++i) {
      gload16(&lds8[b * 16384 + i * 4096 + wid * 1024], srcA[i] + t * 64);
      gload16(&lds8[b * 16384 + 8192 + i * 4096 + wid * 1024], srcB[i] + t * 64);
    }
  };

  stageTo(0, 0);
  union Frag { v4i v; long long ll[2]; };
  const int NT = K >> 6;
  for (int t = 0; t < NT; ++t) {
    const int cur = t & 1;
    if (t + 1 < NT) {
      stageTo(cur ^ 1, t + 1);
      asm volatile("s_waitcnt vmcnt(4)" ::: "memory");
    } else {
      asm volatile("s_waitcnt vmcnt(0)" ::: "memory");
    }
    __builtin_amdgcn_s_barrier();
    const u8* Ab = &lds8[cur * 16384];
    const u8* Bb = Ab + 8192;
    Frag fa[4], fb[4];
    #pragma unroll
    for (int mi = 0; mi < 4; ++mi) fa[mi].v = *(const v4i*)(Ab + aoff[mi]);
    #pragma unroll
    for (int ni = 0; ni < 4; ++ni) fb[ni].v = *(const v4i*)(Bb + boff[ni]);
    __builtin_amdgcn_s_setprio(1);
    #pragma unroll
    for (int mi = 0; mi < 4; ++mi)
      #pragma unroll
      for (int ni = 0; ni < 4; ++ni)
        acc[mi][ni] = __builtin_amdgcn_mfma_f32_16x16x32_fp8_fp8(fa[mi].ll[0], fb[ni].ll[0], acc[mi][ni], 0, 0, 0);
    __builtin_amdgcn_s_setprio(0);
    asm volatile("s_waitcnt lgkmcnt(0)" ::: "memory");
    __builtin_amdgcn_sched_barrier(0);
    __builtin_amdgcn_s_barrier();
    __builtin_amdgcn_s_setprio(1);
    #pragma unroll
    for (int mi = 0; mi < 4; ++mi)
      #pragma unroll
      for (int ni = 0; ni < 4; ++ni)
        acc[mi][ni] = __builtin_amdgcn_mfma_f32_16x16x32_fp8_fp8(fa[mi].ll[1], fb[ni].ll[1], acc[mi][ni], 0, 0, 0);
    __builtin_amdgcn_s_setprio(0);
  }

  #pragma unroll
  for (int mi = 0; mi < 4; ++mi)
    #pragma unroll
    for (int ni = 0; ni < 4; ++ni)
      #pragma unroll
      for (int r = 0; r < 4; ++r) {
        int grow = m0 + wm * 64 + mi * 16 + lq * 4 + r;
        int gcol = n0 + wn * 64 + ni * 16 + lc;
        size_t idx = (size_t)grow * ldc + gcol;
        float vv = acc[mi][ni][r] * 0.015625f;
        if constexpr (EPI == EPI_BF16) {
          Cbf[idx] = f2bf(vv);
        } else if constexpr (EPI == EPI_OEMB) {
          int t_ = grow & 15, bn = grow >> 4;
          int tok = (t_ == 0) ? rs.ftok[bn] : cMASK;
          float kf = (float)keepArr[bn];
          Cf32[idx] = rs.emb[(size_t)tok * cD + gcol] + vv * kf;
        } else {  // EPI_DOWNACC
          Cf32[idx] += vv;
        }
      }
}

// ---------------------------------------------------------------------------
__global__ void k_rope(u16* __restrict__ qb, u16* __restrict__ kb,
                       const int* __restrict__ anchors, const int* __restrict__ cpos) {
  int r = blockIdx.x;
  int which = (r >= MKV);
  int rr = which ? r - MKV : r;
  int j = rr % 17, bn = rr / 17;
  if (!which && j == 0) return;
  u16* buf = which ? kb : qb;
  int pos = (which && j == 0) ? cpos[bn] : (anchors[bn] + j - 1);
  float fp = (float)pos;
  for (int p = threadIdx.x; p < cH * 64; p += 256) {
    int h = p >> 6, i = p & 63;
    size_t base = (size_t)rr * cD + h * cHD;
    float x1 = bf2f(buf[base + i]);
    float x2 = bf2f(buf[base + 64 + i]);
    float freq = powf(10000.0f, -((float)(2 * i)) / 128.0f);
    float ang = fp * freq;
    float sn = sinf(ang), cn = cosf(ang);
    buf[base + i]      = f2bf(x1 * cn - x2 * sn);
    buf[base + 64 + i] = f2bf(x2 * cn + x1 * sn);
  }
}

// Attention. Writes attn-out compact fp8 perm8 (token rows).
__global__ void k_attn(u16* __restrict__ qb, const u16* __restrict__ kb,
                       const u16* __restrict__ vb, u8* __restrict__ ao8) {
  int blk = blockIdx.x;
  int h = blk % cH, bn = blk / cH;
  __shared__ float qs[16][128], ks[17][128], vs[17][128], ps[16][18];
  int lane = threadIdx.x;
  for (int e = lane; e < 16 * 128; e += 64) {
    int r = e >> 7, d = e & 127;
    qs[r][d] = bf2f(qb[((size_t)(bn * 17 + 1 + r)) * cD + h * cHD + d]);
  }
  for (int e = lane; e < 17 * 128; e += 64) {
    int r = e >> 7, d = e & 127;
    ks[r][d] = bf2f(kb[((size_t)(bn * 17 + r)) * cD + h * cHD + d]);
    vs[r][d] = bf2f(vb[((size_t)(bn * 17 + r)) * cD + h * cHD + d]);
  }
  __syncthreads();
  for (int e = lane; e < 16 * 17; e += 64) {
    int qi = e / 17, ki = e % 17;
    float s = 0.f;
    for (int d = 0; d < 128; ++d) s += qs[qi][d] * ks[ki][d];
    ps[qi][ki] = s * 0.08838834764831845f;
  }
  __syncthreads();
  if (lane < 16) {
    float m = -3e38f;
    for (int kk = 0; kk < 17; ++kk) m = fmaxf(m, ps[lane][kk]);
    float s = 0.f;
    for (int kk = 0; kk < 17; ++kk) { float e_ = __expf(ps[lane][kk] - m); ps[lane][kk] = e_; s += e_; }
    float is = 1.0f / s;
    for (int kk = 0; kk < 17; ++kk) ps[lane][kk] *= is;
  }
  __syncthreads();
  for (int e = lane; e < 16 * 128; e += 64) {
    int qi = e >> 7, d = e & 127;
    float s = 0.f;
    for (int kk = 0; kk < 17; ++kk) s += ps[qi][kk] * vs[kk][d];
    ao8[perm8((size_t)(bn * 16 + qi) * cD + h * cHD + d)] = f2fp8(s);
  }
}

__global__ void k_tgt(const u16* __restrict__ hout, const float* __restrict__ Wlm,
                      const int* __restrict__ ids, const int* __restrict__ anchors,
                      int* __restrict__ tgt_tok, float* __restrict__ tgt_logit) {
  int w = threadIdx.x >> 6, lane = threadIdx.x & 63;
  int m = blockIdx.x * 4 + w;
  int bn = m >> 4, t = m & 15, b = bn / cNA;
  int label = anchors[bn] + t;
  int sl = (label < cS - 1) ? label : (cS - 1);
  int tok = ids[(size_t)b * cS + sl];
  const u16* hr = hout + (size_t)m * cD;
  const float* wr = Wlm + (size_t)tok * cD;
  float s = 0.f;
  for (int d = lane; d < cD; d += 64) s += bf2f(hr[d]) * wr[d];
  s = waveSum(s);
  if (lane == 0) { tgt_tok[m] = tok; tgt_logit[m] = s; }
}

__global__ void k_combine(const v4f* __restrict__ partials, const int* __restrict__ tgt_tok,
                          const float* __restrict__ tgt_logit, const int* __restrict__ keepArr,
                          const int* __restrict__ anchors, const float* __restrict__ lmask,
                          float* __restrict__ tokOut, int nch) {
  int m = blockIdx.x;
  int tid = threadIdx.x, lane = tid & 63, w = tid >> 6;
  float cm = -3.0e38f, cs = 0.f; int ca = 0x7fffffff;
  if (tid < nch) {
    v4f rec = partials[(size_t)m * nch + tid];
    cm = rec[0]; cs = rec[1]; ca = __float_as_int(rec[2]);
  }
  float gm = cm; int ga = ca;
  #pragma unroll
  for (int off = 1; off < 64; off <<= 1) {
    float om = __shfl_xor(gm, off); int oa = __shfl_xor(ga, off);
    if (om > gm || (om == gm && oa < ga)) { gm = om; ga = oa; }
  }
  __shared__ float wmx[4]; __shared__ int wax[4]; __shared__ float wsm[4];
  if (lane == 0) { wmx[w] = gm; wax[w] = ga; }
  __syncthreads();
  if (tid == 0) {
    for (int i = 1; i < 4; ++i)
      if (wmx[i] > wmx[0] || (wmx[i] == wmx[0] && wax[i] < wax[0])) { wmx[0] = wmx[i]; wax[0] = wax[i]; }
  }
  __syncthreads();
  gm = wmx[0]; ga = wax[0];
  float s = (tid < nch) ? cs * __expf(cm - gm) : 0.f;
  s = waveSum(s);
  if (lane == 0) wsm[w] = s;
  __syncthreads();
  if (tid == 0) {
    float gs = wsm[0] + wsm[1] + wsm[2] + wsm[3];
    float logZ = gm + logf(gs);
    int bn = m >> 4, t = m & 15, b = bn / cNA;
    int label = anchors[bn] + t;
    int sl = (label < cS - 1) ? label : (cS - 1);
    float wgt = (float)keepArr[bn] * ((t > 0) ? 1.f : 0.f) * ((label < cS) ? 1.f : 0.f) *
                lmask[(size_t)b * cS + sl];
    float lp = tgt_logit[m] - logZ;
    int tg = tgt_tok[m];
    tokOut[m * 4 + 0] = lp * wgt;
    tokOut[m * 4 + 1] = wgt;
    tokOut[m * 4 + 2] = ((ga == tg) && (wgt > 0.5f)) ? 1.f : 0.f;
    tokOut[m * 4 + 3] = 0.f;
  }
}

__global__ void k_final(const float* __restrict__ tokOut, float* __restrict__ outp) {
  int tid = threadIdx.x;
  float swl = 0.f, sw = 0.f, sm = 0.f;
  for (int m = tid; m < MTOK; m += 256) {
    swl += tokOut[m * 4 + 0];
    sw  += tokOut[m * 4 + 1];
    sm  += tokOut[m * 4 + 2];
  }
  swl = waveSum(swl); sw = waveSum(sw); sm = waveSum(sm);
  __shared__ float r0[4], r1[4], r2[4];
  int lane = tid & 63, w = tid >> 6;
  if (lane == 0) { r0[w] = swl; r1[w] = sw; r2[w] = sm; }
  __syncthreads();
  if (tid == 0) {
    float a = r0[0] + r0[1] + r0[2] + r0[3];
    float b = r1[0] + r1[1] + r1[2] + r1[3];
    float c = r2[0] + r2[1] + r2[2] + r2[3];
    float denom = b + 1e-6f;
    float loss = -a / denom;
    float acc  = c / denom;
    if (b == 0.0f) loss = -300.0f;
    outp[0] = loss;
    outp[1] = acc;
  }
}

__global__ void k_sentinel(float* outp) {
  if (threadIdx.x == 0) { outp[0] = -777.0f; outp[1] = -777.0f; }
}

// ---------------------------------------------------------------------------
extern "C" void kernel_launch(void* const* d_in, const int* in_sizes, int n_in,
                              void* d_out, int out_size, void* d_ws, size_t ws_size,
                              hipStream_t stream) {
  const int*   ids   = (const int*)  d_in[0];
  const float* hs    = (const float*)d_in[1];
  const float* lmask = (const float*)d_in[2];
  const float* rv    = (const float*)d_in[3];
  const float* emb   = (const float*)d_in[4];
  const float* wlm   = (const float*)d_in[5];
  const float* wq    = (const float*)d_in[6];
  const float* wk    = (const float*)d_in[7];
  const float* wv    = (const float*)d_in[8];
  const float* wo    = (const float*)d_in[9];
  const float* wg    = (const float*)d_in[10];
  const float* wu    = (const float*)d_in[11];
  const float* wd    = (const float*)d_in[12];
  const float* nattn = (const float*)d_in[13];
  const float* nmlp  = (const float*)d_in[14];
  const float* nout  = (const float*)d_in[15];
  const float* nchs  = (const float*)d_in[16];
  (void)in_sizes; (void)n_in; (void)out_size;

  float* outp = (float*)d_out;

  char* wsb = (char*)d_ws;
  size_t off = 0;
  auto alloc = [&](size_t bytes) -> void* {
    void* p = wsb + off;
    off = (off + bytes + 255) & ~(size_t)255;
    return p;
  };
  int*   anchors = (int*)  alloc((size_t)cB * cNA * 4);
  int*   keepA   = (int*)  alloc((size_t)cB * cNA * 4);
  int*   ftok    = (int*)  alloc((size_t)cB * cNA * 4);
  int*   cpos    = (int*)  alloc((size_t)cB * cNA * 4);
  int*   self    = (int*)  alloc((size_t)cB * NCAND * 4);
  float* rowinv  = (float*)alloc((size_t)MKV * 4);
  int*   ttok    = (int*)  alloc((size_t)MTOK * 4);
  float* tlogit  = (float*)alloc((size_t)MTOK * 4);
  float* tokOut  = (float*)alloc((size_t)MTOK * 4 * 4);

  const size_t szQ  = (size_t)MKV * cD * 2;           // 17.8 MB (q -> h -> h_out)
  const size_t szX  = (size_t)MTOK * cD * 4;          // 33.6 MB (fp32 residual)
  u16* qb = (u16*)alloc(szQ);
  const size_t a1off = off;

  RmsSrc rs{hs, emb, nattn, nchs, rowinv, ftok, cpos};

  // common head
  k_select <<<dim3(cB * 16), 256, 0, stream>>>(lmask, rv, self);
  k_anchors<<<dim3(cB),      256, 0, stream>>>(lmask, self, ids, anchors, keepA, ftok, cpos);

  // ---------------- fast tier
  size_t kvb_off  = a1off;                            // kv8 fp8: 8.9 MB
  size_t a1f_off  = (kvb_off + szQ + 255) & ~(size_t)255;
  size_t a1f_sz   = 2 * szQ > (szX + (size_t)MTOK * 4096 * 2) ? 2 * szQ
                                                             : (szX + (size_t)MTOK * 4096 * 2);
  size_t wreg_off = (a1f_off + a1f_sz + 255) & ~(size_t)255;
  size_t wreg_sz  = (size_t)cV * cD * 2;              // 131 MB (largest stage)
  size_t need_fast = wreg_off + wreg_sz;

  if (need_fast <= ws_size) {
    u8*    kv8   = (u8*)(wsb + kvb_off);
    u16*   kb    = (u16*)(wsb + a1f_off);
    u16*   vb    = (u16*)(wsb + a1f_off + szQ);
    float* xb    = (float*)(wsb + a1f_off);
    u8*    ao8   = (u8*)(wsb + a1f_off + 2 * szQ);
    u8*    cbuf8 = (u8*)(wsb + a1f_off + 2 * szQ + (size_t)MTOK * cD);
    v4f*   parts = (v4f*)(wsb + a1f_off);             // lm-head stage (xb dead)
    u8*    h8    = (u8*)(wsb + a1f_off + (size_t)16 * 1024 * 1024);
    u16*   hb    = qb;
    u16*   houtb = qb;
    u16*   wT    = (u16*)(wsb + wreg_off);
    const size_t szDD = (size_t)cD * cD;
    u8* wq8 = (u8*)wT;        u8* wk8 = wq8 + szDD;
    u8* wv8 = wq8 + 2 * szDD; u8* wo8 = wq8 + 3 * szDD;
    const size_t szDF = (size_t)cD * cDFF;
    u8* wgu8 = (u8*)wT;                               // stage 2: 33.5 MB
    u8* wd8  = (u8*)wT + 2 * szDF;
    u8* h8m  = (u8*)wT + 3 * szDF;
    u8* wlm8 = (u8*)wT;                               // stage 3: 65.5 MB

    k_build2<<<dim3(MKV), 256, 0, stream>>>(hs, emb, nattn, nchs, ftok, cpos, kv8);

    k_tconv8<<<dim3(32, 32), 256, 0, stream>>>(wq, wq8, cD, cD, -1, 64.0f);
    k_tconv8<<<dim3(32, 32), 256, 0, stream>>>(wk, wk8, cD, cD, -1, 64.0f);
    k_tconv8<<<dim3(32, 32), 256, 0, stream>>>(wv, wv8, cD, cD, -1, 64.0f);
    k_tconv8<<<dim3(32, 32), 256, 0, stream>>>(wo, wo8, cD, cD, -1, 64.0f);

    k_gemm9<EPI_BF16><<<dim3(MKV / 128, cD / 128), 256, 0, stream>>>(
        kv8, wq8, qb, nullptr, nullptr, rs, cD, cD, cD);
    k_gemm9<EPI_BF16><<<dim3(MKV / 128, cD / 128), 256, 0, stream>>>(
        kv8, wk8, kb, nullptr, nullptr, rs, cD, cD, cD);
    k_gemm9<EPI_BF16><<<dim3(MKV / 128, cD / 128), 256, 0, stream>>>(
        kv8, wv8, vb, nullptr, nullptr, rs, cD, cD, cD);

    k_rope<<<dim3(2 * MKV), 256, 0, stream>>>(qb, kb, anchors, cpos);
    k_attn<<<dim3(cB * cNA * cH), 64, 0, stream>>>(qb, kb, vb, ao8);

    k_gemm9<EPI_OEMB><<<dim3(MTOK / 128, cD / 128), 256, 0, stream>>>(
        ao8, wo8, nullptr, xb, keepA, rs, cD, cD, cD);

    k_rms<<<dim3(MTOK), 256, 0, stream>>>(xb, nmlp, hb);
    k_cvt8<<<dim3(1024), 256, 0, stream>>>(hb, h8m, (long)MTOK * cD);

    k_tconv8<<<dim3(128, 32), 256, 0, stream>>>(wg, wgu8, cD, cDFF, 0, 64.0f);
    k_tconv8<<<dim3(128, 32), 256, 0, stream>>>(wu, wgu8, cD, cDFF, 16, 64.0f);
    k_tconv8<<<dim3(32, 128), 256, 0, stream>>>(wd, wd8, cDFF, cD, -1, 64.0f);

    for (int cb = 0; cb < cDFF; cb += 4096) {
      k_gemm8<EPI_GLU><<<dim3(MTOK / 256, 32), 512, 0, stream>>>(
          h8m, wgu8 + (size_t)cb * 2 * cD, cbuf8, nullptr, cD, 4096, 0);
      k_gemm9<EPI_DOWNACC><<<dim3(MTOK / 128, cD / 128), 256, 0, stream>>>(
          cbuf8, wd8 + cb, nullptr, xb, nullptr, rs, 4096, cDFF, cD);
    }

    k_rms<<<dim3(MTOK), 256, 0, stream>>>(xb, nout, houtb);

    k_tgt<<<dim3(MTOK / 4), 256, 0, stream>>>(houtb, wlm, ids, anchors, ttok, tlogit);

    k_cvt8 <<<dim3(1024), 256, 0, stream>>>(houtb, h8, (long)MTOK * cD);
    k_conv8<<<dim3(2048), 256, 0, stream>>>(wlm, wlm8, (long)cV * cD, 64.0f);
    k_gemm8<EPI_STATS><<<dim3(MTOK / 256, NCH2), 512, 0, stream>>>(
        h8, wlm8, nullptr, parts, cD, 0, NCH2);

    k_combine<<<dim3(MTOK), 256, 0, stream>>>(parts, ttok, tlogit, keepA, anchors, lmask, tokOut, NCH2);
    k_final  <<<dim3(1), 256, 0, stream>>>(tokOut, outp);
    return;
  }

  // ---------------- fallback: signal insufficient workspace
  k_sentinel<<<dim3(1), 64, 0, stream>>>(outp);
}